// Round 2
// baseline (480.436 us; speedup 1.0000x reference)
//
#include <hip/hip_runtime.h>
#include <hip/hip_fp16.h>
#include <math.h>

// GAT 2-layer + BN + classifier, MI355X.
// R12: k_agg split into k_wts (softmax weights, lane-parallel, true max) +
// k_gather (pure gather-FMA). Weights+src packed into one u32/edge:
// (idx<<15)|fp16bits (weight in [0,1] -> sign bit 0 -> 15 bits lossless).
// k_gather per edge: 1 readlane + SALU unpack + SGPR-base gather + 1 hfma2.
// pkbuf/invb alias the dead `bucket` workspace. 12 launches.

#define CDIM 128
#define NCLS_ 40
#define NEG_SLOPE_ 0.2f
#define BN_EPS_ 1e-5f
#define BRNG 256        // nodes per bucket (power of 2)
#define BCAP 6144       // max edges per bucket (mean 4096)
#define EPB 16          // edges per thread in k_binA (4096 per block)

using short8  = __attribute__((ext_vector_type(8))) short;
using short4v = __attribute__((ext_vector_type(4))) short;
using f32x4   = __attribute__((ext_vector_type(4))) float;

static __device__ __forceinline__ float lrelu(float a) {
    return a > 0.f ? a : NEG_SLOPE_ * a;
}
// fp32 -> bf16 round-to-nearest-even
static __device__ __forceinline__ short f2bf(float f) {
    unsigned u = __float_as_uint(f);
    u += 0x7fffu + ((u >> 16) & 1u);
    return (short)(u >> 16);
}
static __device__ __forceinline__ float bf_lo(unsigned u) { return __uint_as_float(u << 16); }
static __device__ __forceinline__ float bf_hi(unsigned u) { return __uint_as_float(u & 0xffff0000u); }
static __device__ __forceinline__ __half2 u2h2(unsigned u) { return __builtin_bit_cast(__half2, u); }

// ---------------- setup: cursors=0, bn sums=0, offs[n], W->bf16^T ----------
__global__ void k_setup(int* bcur, float* bnsum, int NB, int n, int E, int* offs,
                        const float* __restrict__ W1, const float* __restrict__ W2,
                        const float* __restrict__ Wc,
                        short* __restrict__ Wt1, short* __restrict__ Wt2,
                        short* __restrict__ Wtc) {
    int i = blockIdx.x * blockDim.x + threadIdx.x;
    if (i < NB) bcur[i] = 0;
    if (i < 512) bnsum[i] = 0.f;
    if (i == 0) offs[n] = E + n;
    if (i < 128 * 128) {
        int k = i >> 7, nn = i & 127;
        Wt1[nn * 128 + k] = f2bf(W1[i]);
        Wt2[nn * 128 + k] = f2bf(W2[i]);
    }
    if (i < 48 * 128) {             // padded bf16 Wc^T [48][128]
        int nn = i >> 7, k = i & 127;
        Wtc[i] = (nn < NCLS_) ? f2bf(Wc[k * NCLS_ + nn]) : (short)0;
    }
}

// ---------------- two-level binning into dst-range buckets -----------------
__global__ __launch_bounds__(256) void k_binA(
    const int* __restrict__ src, const int* __restrict__ dst, int E,
    int* __restrict__ bcur, uint2* __restrict__ bucket, int NB)
{
    __shared__ int hist[400];
    __shared__ int base[400];
    int t = threadIdx.x;
    long e0 = (long)blockIdx.x * (256 * EPB) + t;

    for (int i = t; i < NB; i += 256) hist[i] = 0;
    __syncthreads();

    int sv[EPB], dv[EPB];
    #pragma unroll
    for (int i = 0; i < EPB; i++) {
        long e = e0 + (long)i * 256;
        if (e < E) {
            sv[i] = src[e]; dv[i] = dst[e];
            atomicAdd(&hist[dv[i] >> 8], 1);
        } else dv[i] = -1;
    }
    __syncthreads();

    for (int i = t; i < NB; i += 256) {
        int h = hist[i];
        base[i] = (h > 0) ? atomicAdd(&bcur[i], h) : 0;
    }
    __syncthreads();
    for (int i = t; i < NB; i += 256) hist[i] = 0;   // reuse as cursor
    __syncthreads();

    #pragma unroll
    for (int i = 0; i < EPB; i++) {
        if (dv[i] >= 0) {
            int b = dv[i] >> 8;
            int pos = base[b] + atomicAdd(&hist[b], 1);
            if (pos < BCAP)
                bucket[(size_t)b * BCAP + pos] =
                    make_uint2((unsigned)sv[i], (unsigned)dv[i]);
        }
    }
}

// ---------------- per-bucket CSR build in LDS ------------------------------
__global__ __launch_bounds__(256) void k_fillB(
    const uint2* __restrict__ bucket, const int* __restrict__ bcur,
    int n, int NB, int* __restrict__ offs, int* __restrict__ csr)
{
    __shared__ int hist[256];
    __shared__ int scanb[256];
    __shared__ int cur[256];
    __shared__ int buf[BCAP + BRNG];
    int b = blockIdx.x, t = threadIdx.x;
    int node0 = b << 8;
    int nodesIn = min(BRNG, n - node0);
    int cnt = min(bcur[b], BCAP);
    const uint2* mybkt = bucket + (size_t)b * BCAP;

    int part = 0;
    for (int j = t; j < b; j += 256) part += min(bcur[j], BCAP);
    scanb[t] = part; __syncthreads();
    for (int s2 = 128; s2 > 0; s2 >>= 1) {
        if (t < s2) scanb[t] += scanb[t + s2];
        __syncthreads();
    }
    int base = scanb[0] + node0;
    __syncthreads();

    hist[t] = 0; __syncthreads();
    for (int e2 = t; e2 < cnt; e2 += 256)
        atomicAdd(&hist[mybkt[e2].y & 255], 1);
    __syncthreads();

    int v = hist[t] + ((t < nodesIn) ? 1 : 0);
    scanb[t] = v; __syncthreads();
    for (int d = 1; d < 256; d <<= 1) {
        int x2 = (t >= d) ? scanb[t - d] : 0;
        __syncthreads();
        scanb[t] += x2;
        __syncthreads();
    }
    int lo = scanb[t] - v;
    if (t < nodesIn) {
        offs[node0 + t] = base + lo;
        buf[lo] = node0 + t;          // self-loop occupies slot 0
        cur[t] = lo + 1;
    }
    __syncthreads();

    for (int e2 = t; e2 < cnt; e2 += 256) {
        uint2 ed = mybkt[e2];
        int pos = atomicAdd(&cur[ed.y & 255], 1);
        buf[pos] = (int)ed.x;
    }
    __syncthreads();

    int tot = cnt + nodesIn;
    for (int j2 = t; j2 < tot; j2 += 256) csr[base + j2] = buf[j2];
}

// ---------------- MFMA GEMM: Hh(f16) = act(X) @ W, alpha fused -------------
__global__ __launch_bounds__(256) void k_gemm_mfma(
    const float* __restrict__ Xf, const unsigned* __restrict__ Xb,
    const short* __restrict__ Wt,
    const float* __restrict__ bnsum, const float* __restrict__ gamma,
    const float* __restrict__ beta, float invn,
    const float* __restrict__ av_s, const float* __restrict__ av_d,
    short* __restrict__ Hh, float* __restrict__ alpha_s, float* __restrict__ alpha_d,
    int n, int fuse)
{
    __shared__ short As[64 * 128];    // 16.4 KB (reused as H transpose buffer)
    __shared__ short Bs[128 * 128];   // 32.8 KB
    __shared__ float part_s[4][64];
    __shared__ float part_d[4][64];
    int t = threadIdx.x;
    int row0 = blockIdx.x * 64;

    for (int j = 0; j < 8; j++) {
        int idx = j * 256 + t;
        int nn = idx >> 4, cc = idx & 15;
        *(short8*)(Bs + nn * 128 + cc * 8) = *(const short8*)(Wt + nn * 128 + cc * 8);
    }
    float4 sc4 = make_float4(1.f, 1.f, 1.f, 1.f);
    float4 sh4 = make_float4(0.f, 0.f, 0.f, 0.f);
    if (fuse) {
        int cb = (t & 31) * 4;
        float4 s0 = *(const float4*)(bnsum + cb);
        float4 s1 = *(const float4*)(bnsum + 128 + cb);
        float4 gm = *(const float4*)(gamma + cb);
        float4 bt = *(const float4*)(beta + cb);
        float mean, var;
        mean = s0.x * invn; var = fmaxf(s1.x * invn - mean * mean, 0.f);
        sc4.x = gm.x * rsqrtf(var + BN_EPS_); sh4.x = bt.x - mean * sc4.x;
        mean = s0.y * invn; var = fmaxf(s1.y * invn - mean * mean, 0.f);
        sc4.y = gm.y * rsqrtf(var + BN_EPS_); sh4.y = bt.y - mean * sc4.y;
        mean = s0.z * invn; var = fmaxf(s1.z * invn - mean * mean, 0.f);
        sc4.z = gm.z * rsqrtf(var + BN_EPS_); sh4.z = bt.z - mean * sc4.z;
        mean = s0.w * invn; var = fmaxf(s1.w * invn - mean * mean, 0.f);
        sc4.w = gm.w * rsqrtf(var + BN_EPS_); sh4.w = bt.w - mean * sc4.w;
    }
    for (int j = 0; j < 8; j++) {
        int idx = j * 256 + t;
        int r = idx >> 5, k4 = idx & 31;
        int gr = row0 + r;
        float4 xv = make_float4(0.f, 0.f, 0.f, 0.f);
        if (fuse) {
            if (gr < n) {
                uint2 u = *(const uint2*)(Xb + (size_t)gr * 64 + k4 * 2);
                xv.x = bf_lo(u.x); xv.y = bf_hi(u.x);
                xv.z = bf_lo(u.y); xv.w = bf_hi(u.y);
            }
            xv.x = fmaxf(fmaf(xv.x, sc4.x, sh4.x), 0.f);
            xv.y = fmaxf(fmaf(xv.y, sc4.y, sh4.y), 0.f);
            xv.z = fmaxf(fmaf(xv.z, sc4.z, sh4.z), 0.f);
            xv.w = fmaxf(fmaf(xv.w, sc4.w, sh4.w), 0.f);
        } else {
            if (gr < n) xv = *(const float4*)(Xf + (size_t)gr * CDIM + k4 * 4);
        }
        short4v o;
        o.x = f2bf(xv.x); o.y = f2bf(xv.y); o.z = f2bf(xv.z); o.w = f2bf(xv.w);
        *(short4v*)(As + r * 128 + k4 * 4) = o;
    }
    __syncthreads();

    int w = t >> 6, lane = t & 63, q = lane >> 4, c = lane & 15;
    f32x4 zero = {0.f, 0.f, 0.f, 0.f};
    f32x4 acc[4][2];
    for (int i = 0; i < 4; i++) { acc[i][0] = zero; acc[i][1] = zero; }

    for (int ks = 0; ks < 4; ks++) {
        int k0 = ks * 32 + q * 8;
        short8 a0 = *(short8*)(As + (c) * 128 + k0);
        short8 a1 = *(short8*)(As + (16 + c) * 128 + k0);
        short8 a2 = *(short8*)(As + (32 + c) * 128 + k0);
        short8 a3 = *(short8*)(As + (48 + c) * 128 + k0);
        short8 b0 = *(short8*)(Bs + (w * 32 + c) * 128 + k0);
        short8 b1 = *(short8*)(Bs + (w * 32 + 16 + c) * 128 + k0);
        acc[0][0] = __builtin_amdgcn_mfma_f32_16x16x32_bf16(a0, b0, acc[0][0], 0, 0, 0);
        acc[1][0] = __builtin_amdgcn_mfma_f32_16x16x32_bf16(a1, b0, acc[1][0], 0, 0, 0);
        acc[2][0] = __builtin_amdgcn_mfma_f32_16x16x32_bf16(a2, b0, acc[2][0], 0, 0, 0);
        acc[3][0] = __builtin_amdgcn_mfma_f32_16x16x32_bf16(a3, b0, acc[3][0], 0, 0, 0);
        acc[0][1] = __builtin_amdgcn_mfma_f32_16x16x32_bf16(a0, b1, acc[0][1], 0, 0, 0);
        acc[1][1] = __builtin_amdgcn_mfma_f32_16x16x32_bf16(a1, b1, acc[1][1], 0, 0, 0);
        acc[2][1] = __builtin_amdgcn_mfma_f32_16x16x32_bf16(a2, b1, acc[2][1], 0, 0, 0);
        acc[3][1] = __builtin_amdgcn_mfma_f32_16x16x32_bf16(a3, b1, acc[3][1], 0, 0, 0);
    }

    float as0 = av_s[w * 32 + c],      as1 = av_s[w * 32 + 16 + c];
    float ad0 = av_d[w * 32 + c],      ad1 = av_d[w * 32 + 16 + c];
    #pragma unroll
    for (int mt = 0; mt < 4; mt++) {
        #pragma unroll
        for (int r = 0; r < 4; r++) {
            float v0 = acc[mt][0][r], v1 = acc[mt][1][r];
            float ps = v0 * as0 + v1 * as1;
            float pd = v0 * ad0 + v1 * ad1;
            #pragma unroll
            for (int off = 1; off < 16; off <<= 1) {
                ps += __shfl_xor(ps, off);
                pd += __shfl_xor(pd, off);
            }
            if (c == 0) {
                part_s[w][mt * 16 + q * 4 + r] = ps;
                part_d[w][mt * 16 + q * 4 + r] = pd;
            }
        }
    }
    __syncthreads();

    // transpose H as packed fp16 (consumed only by k_gather's __hfma2 path)
    short* Hs = As;
    #pragma unroll
    for (int mt = 0; mt < 4; mt++)
        #pragma unroll
        for (int nt = 0; nt < 2; nt++)
            #pragma unroll
            for (int r = 0; r < 4; r++)
                Hs[(mt * 16 + q * 4 + r) * 128 + w * 32 + nt * 16 + c] =
                    (short)__half_as_ushort(__float2half_rn(acc[mt][nt][r]));

    if (t < 64) {
        int row = row0 + t;
        if (row < n) {
            alpha_s[row] = part_s[0][t] + part_s[1][t] + part_s[2][t] + part_s[3][t];
            alpha_d[row] = part_d[0][t] + part_d[1][t] + part_d[2][t] + part_d[3][t];
        }
    }
    __syncthreads();

    for (int j = 0; j < 4; j++) {
        int idx = j * 256 + t;
        int r = idx >> 4, cc = idx & 15;
        int gr = row0 + r;
        if (gr < n)
            *(short8*)(Hh + (size_t)gr * 128 + cc * 8) = *(short8*)(Hs + r * 128 + cc * 8);
    }
}

// ---------------- Pass A: softmax weights, packed (idx<<15)|fp16 -----------
// One wave per node, lane per edge. True max per node (no online rescale).
// Weight e = exp(a-m) in [0,1]: fp16 sign bit 0 -> 15 bits lossless.
__global__ __launch_bounds__(256) void k_wts(
    const int* __restrict__ offs, const int* __restrict__ csr,
    const float* __restrict__ alpha_s, const float* __restrict__ alpha_d,
    unsigned* __restrict__ pkbuf, float* __restrict__ invb, int n)
{
    int i = blockIdx.x * 4 + (threadIdx.x >> 6);
    int lane = threadIdx.x & 63;
    if (i >= n) return;
    int o0 = offs[i], o1 = offs[i + 1];
    float adi = alpha_d[i];
    int deg = o1 - o0;

    if (deg <= 64) {                 // common path (deg ~ Poisson(16)+1)
        int j = o0 + lane;
        bool v = j < o1;
        int sj = v ? csr[j] : 0;
        float a = v ? lrelu(alpha_s[sj] + adi) : -1e30f;
        float m = a;
        #pragma unroll
        for (int o = 32; o > 0; o >>= 1) m = fmaxf(m, __shfl_xor(m, o));
        float e = v ? __expf(a - m) : 0.f;
        float se = e;
        #pragma unroll
        for (int o = 32; o > 0; o >>= 1) se += __shfl_xor(se, o);
        if (v) {
            unsigned h = (unsigned)__half_as_ushort(__float2half_rn(e));
            pkbuf[j] = ((unsigned)sj << 15) | h;
        }
        if (lane == 0) invb[i] = 1.f / se;
    } else {                          // rare: two-phase, global max
        float m = -1e30f;
        for (int c0 = o0; c0 < o1; c0 += 64) {
            int j = c0 + lane;
            float a = (j < o1) ? lrelu(alpha_s[csr[j]] + adi) : -1e30f;
            m = fmaxf(m, a);
        }
        #pragma unroll
        for (int o = 32; o > 0; o >>= 1) m = fmaxf(m, __shfl_xor(m, o));
        float se = 0.f;
        for (int c0 = o0; c0 < o1; c0 += 64) {
            int j = c0 + lane;
            if (j < o1) {
                int sj = csr[j];
                float a = lrelu(alpha_s[sj] + adi);
                float e = __expf(a - m);
                se += e;
                unsigned h = (unsigned)__half_as_ushort(__float2half_rn(e));
                pkbuf[j] = ((unsigned)sj << 15) | h;
            }
        }
        #pragma unroll
        for (int o = 32; o > 0; o >>= 1) se += __shfl_xor(se, o);
        if (lane == 0) invb[i] = 1.f / se;
    }
}

// ---------------- Pass B: pure gather-FMA ----------------------------------
// Per edge: 1 readlane (packed word -> SGPR), SALU unpack (idx = pk>>15,
// w = pk&0x7fff duplicated), SGPR-base gather, 1 v_pk_fma_f16.
// Tail lanes carry pk=0 -> row 0, weight 0: safe by construction.
__global__ __launch_bounds__(256) void k_gather(
    const unsigned* __restrict__ Hh, const int* __restrict__ offs,
    const unsigned* __restrict__ pkbuf, const float* __restrict__ invb,
    const float* __restrict__ bias, unsigned* __restrict__ Ob, int n)
{
    int i = blockIdx.x * 4 + (threadIdx.x >> 6);
    int lane = threadIdx.x & 63;
    if (i >= n) return;
    int o0 = offs[i], o1 = offs[i + 1];
    __half2 acc2 = __floats2half2_rn(0.f, 0.f);

    for (int c0 = o0; c0 < o1; c0 += 64) {
        int j = c0 + lane;
        int cnt = min(64, o1 - c0);
        int pk = (j < o1) ? (int)pkbuf[j] : 0;

        unsigned ua[8], ub[8], uc[8];
        int pa[8], pb[8], pc[8];     // uniform (SGPR) packed words
        #pragma unroll
        for (int q = 0; q < 8; q++) {
            pa[q] = __builtin_amdgcn_readlane(pk, q);
            ua[q] = Hh[(size_t)((unsigned)pa[q] >> 15) * 64 + lane];
        }
        if (cnt > 8) {
            #pragma unroll
            for (int q = 0; q < 8; q++) {
                pb[q] = __builtin_amdgcn_readlane(pk, 8 + q);
                ub[q] = Hh[(size_t)((unsigned)pb[q] >> 15) * 64 + lane];
            }
        }
        if (cnt > 16) {
            #pragma unroll
            for (int q = 0; q < 8; q++) {
                pc[q] = __builtin_amdgcn_readlane(pk, 16 + q);
                uc[q] = Hh[(size_t)((unsigned)pc[q] >> 15) * 64 + lane];
            }
        }

        for (int b = 0; b < cnt; b += 24) {
            #pragma unroll
            for (int q = 0; q < 8; q++) {
                unsigned hw = (unsigned)pa[q] & 0x7fffu;
                hw |= hw << 16;
                acc2 = __hfma2(u2h2(ua[q]), u2h2(hw), acc2);
            }
            if (b + 24 < cnt) {
                #pragma unroll
                for (int q = 0; q < 8; q++) {
                    pa[q] = __builtin_amdgcn_readlane(pk, b + 24 + q);
                    ua[q] = Hh[(size_t)((unsigned)pa[q] >> 15) * 64 + lane];
                }
            }
            if (b + 8 < cnt) {
                #pragma unroll
                for (int q = 0; q < 8; q++) {
                    unsigned hw = (unsigned)pb[q] & 0x7fffu;
                    hw |= hw << 16;
                    acc2 = __hfma2(u2h2(ub[q]), u2h2(hw), acc2);
                }
                if (b + 32 < cnt) {
                    #pragma unroll
                    for (int q = 0; q < 8; q++) {
                        pb[q] = __builtin_amdgcn_readlane(pk, b + 32 + q);
                        ub[q] = Hh[(size_t)((unsigned)pb[q] >> 15) * 64 + lane];
                    }
                }
                if (b + 16 < cnt) {
                    #pragma unroll
                    for (int q = 0; q < 8; q++) {
                        unsigned hw = (unsigned)pc[q] & 0x7fffu;
                        hw |= hw << 16;
                        acc2 = __hfma2(u2h2(uc[q]), u2h2(hw), acc2);
                    }
                    if (b + 40 < cnt) {
                        #pragma unroll
                        for (int q = 0; q < 8; q++) {
                            pc[q] = __builtin_amdgcn_readlane(pk, b + 40 + q);
                            uc[q] = Hh[(size_t)((unsigned)pc[q] >> 15) * 64 + lane];
                        }
                    }
                }
            }
        }
    }

    float inv = invb[i];
    float2 af = __half22float2(acc2);
    float2 b2 = *(const float2*)(bias + lane * 2);
    float rx = fmaf(af.x, inv, b2.x);
    float ry = fmaf(af.y, inv, b2.y);
    unsigned pack = ((unsigned)(unsigned short)f2bf(ry) << 16) |
                    (unsigned)(unsigned short)f2bf(rx);
    Ob[(size_t)i * 64 + lane] = pack;
}

// ---------------- BN stats from packed bf16: per-channel sum / sumsq -------
__global__ void k_bnstats(const unsigned* __restrict__ Hb, int n, float* __restrict__ sums) {
    __shared__ float red[4][64][4];
    int w = threadIdx.x & 63;
    int g = threadIdx.x >> 6;
    float slo = 0.f, shi = 0.f, qlo = 0.f, qhi = 0.f;
    for (int r = blockIdx.x * 4 + g; r < n; r += gridDim.x * 4) {
        unsigned u = Hb[(size_t)r * 64 + w];
        float lo = bf_lo(u), hi = bf_hi(u);
        slo += lo; shi += hi; qlo += lo * lo; qhi += hi * hi;
    }
    red[g][w][0] = slo; red[g][w][1] = shi; red[g][w][2] = qlo; red[g][w][3] = qhi;
    __syncthreads();
    if (threadIdx.x < 64) {
        int w2 = threadIdx.x;
        float s0 = 0.f, s1 = 0.f, s2 = 0.f, s3 = 0.f;
        for (int gg = 0; gg < 4; gg++) {
            s0 += red[gg][w2][0]; s1 += red[gg][w2][1];
            s2 += red[gg][w2][2]; s3 += red[gg][w2][3];
        }
        atomicAdd(&sums[2 * w2], s0);
        atomicAdd(&sums[2 * w2 + 1], s1);
        atomicAdd(&sums[128 + 2 * w2], s2);
        atomicAdd(&sums[128 + 2 * w2 + 1], s3);
    }
}

// ---------------- classifier (MFMA): out = relu(bn(G)) @ Wc + bc -----------
__global__ __launch_bounds__(256) void k_cls(
    const unsigned* __restrict__ G, const short* __restrict__ Wtc,
    const float* __restrict__ bc, const float* __restrict__ bnsum,
    const float* __restrict__ gamma, const float* __restrict__ beta, float invn,
    float* __restrict__ out, int n)
{
    __shared__ short As[64 * 128];   // 16.4 KB
    __shared__ short Bs[48 * 128];   // 12.3 KB
    int t = threadIdx.x;
    int row0 = blockIdx.x * 64;

    for (int j = 0; j < 3; j++) {
        int idx = j * 256 + t;       // 768 short8 = 6144 shorts
        *(short8*)(Bs + idx * 8) = *(const short8*)(Wtc + idx * 8);
    }
    float4 sc4, sh4;
    {
        int cb = (t & 31) * 4;
        float4 s0 = *(const float4*)(bnsum + cb);
        float4 s1 = *(const float4*)(bnsum + 128 + cb);
        float4 gm = *(const float4*)(gamma + cb);
        float4 bt = *(const float4*)(beta + cb);
        float mean, var;
        mean = s0.x * invn; var = fmaxf(s1.x * invn - mean * mean, 0.f);
        sc4.x = gm.x * rsqrtf(var + BN_EPS_); sh4.x = bt.x - mean * sc4.x;
        mean = s0.y * invn; var = fmaxf(s1.y * invn - mean * mean, 0.f);
        sc4.y = gm.y * rsqrtf(var + BN_EPS_); sh4.y = bt.y - mean * sc4.y;
        mean = s0.z * invn; var = fmaxf(s1.z * invn - mean * mean, 0.f);
        sc4.z = gm.z * rsqrtf(var + BN_EPS_); sh4.z = bt.z - mean * sc4.z;
        mean = s0.w * invn; var = fmaxf(s1.w * invn - mean * mean, 0.f);
        sc4.w = gm.w * rsqrtf(var + BN_EPS_); sh4.w = bt.w - mean * sc4.w;
    }
    for (int j = 0; j < 8; j++) {
        int idx = j * 256 + t;
        int r = idx >> 5, k4 = idx & 31;
        int gr = row0 + r;
        float4 xv = make_float4(0.f, 0.f, 0.f, 0.f);
        if (gr < n) {
            uint2 u = *(const uint2*)(G + (size_t)gr * 64 + k4 * 2);
            xv.x = bf_lo(u.x); xv.y = bf_hi(u.x);
            xv.z = bf_lo(u.y); xv.w = bf_hi(u.y);
        }
        xv.x = fmaxf(fmaf(xv.x, sc4.x, sh4.x), 0.f);
        xv.y = fmaxf(fmaf(xv.y, sc4.y, sh4.y), 0.f);
        xv.z = fmaxf(fmaf(xv.z, sc4.z, sh4.z), 0.f);
        xv.w = fmaxf(fmaf(xv.w, sc4.w, sh4.w), 0.f);
        short4v o;
        o.x = f2bf(xv.x); o.y = f2bf(xv.y); o.z = f2bf(xv.z); o.w = f2bf(xv.w);
        *(short4v*)(As + r * 128 + k4 * 4) = o;
    }
    __syncthreads();

    int w = t >> 6, lane = t & 63, q = lane >> 4, c = lane & 15;
    f32x4 zero = {0.f, 0.f, 0.f, 0.f};
    f32x4 acc[3] = {zero, zero, zero};
    for (int ks = 0; ks < 4; ks++) {
        int k0 = ks * 32 + q * 8;
        short8 a  = *(short8*)(As + (w * 16 + c) * 128 + k0);
        short8 b0 = *(short8*)(Bs + (c) * 128 + k0);
        short8 b1 = *(short8*)(Bs + (16 + c) * 128 + k0);
        short8 b2 = *(short8*)(Bs + (32 + c) * 128 + k0);
        acc[0] = __builtin_amdgcn_mfma_f32_16x16x32_bf16(a, b0, acc[0], 0, 0, 0);
        acc[1] = __builtin_amdgcn_mfma_f32_16x16x32_bf16(a, b1, acc[1], 0, 0, 0);
        acc[2] = __builtin_amdgcn_mfma_f32_16x16x32_bf16(a, b2, acc[2], 0, 0, 0);
    }
    float bc0 = bc[c], bc1 = bc[16 + c], bc2 = (c < 8) ? bc[32 + c] : 0.f;
    #pragma unroll
    for (int r = 0; r < 4; r++) {
        int row = row0 + w * 16 + q * 4 + r;
        if (row < n) {
            out[(size_t)row * NCLS_ + c]      = acc[0][r] + bc0;
            out[(size_t)row * NCLS_ + 16 + c] = acc[1][r] + bc1;
            if (c < 8) out[(size_t)row * NCLS_ + 32 + c] = acc[2][r] + bc2;
        }
    }
}

// ---------------- launch ---------------------------------------------------
extern "C" void kernel_launch(void* const* d_in, const int* in_sizes, int n_in,
                              void* d_out, int out_size, void* d_ws, size_t ws_size,
                              hipStream_t stream)
{
    const float* x   = (const float*)d_in[0];
    const int*   ei  = (const int*)d_in[1];
    const float* W1  = (const float*)d_in[2];
    const float* as1 = (const float*)d_in[3];
    const float* ad1 = (const float*)d_in[4];
    const float* b1  = (const float*)d_in[5];
    const float* g1  = (const float*)d_in[6];
    const float* be1 = (const float*)d_in[7];
    const float* W2  = (const float*)d_in[8];
    const float* as2 = (const float*)d_in[9];
    const float* ad2 = (const float*)d_in[10];
    const float* b2  = (const float*)d_in[11];
    const float* g2  = (const float*)d_in[12];
    const float* be2 = (const float*)d_in[13];
    const float* Wc  = (const float*)d_in[14];
    const float* bc  = (const float*)d_in[15];
    float* out = (float*)d_out;

    int n = in_sizes[0] / CDIM;     // 100000
    int E = in_sizes[1] / 2;        // 1600000
    const int* src = ei;
    const int* dst = ei + E;
    float invn = 1.f / (float)n;
    int NB = (n + BRNG - 1) / BRNG; // 391

    // workspace layout (64B-aligned chunks)
    char* p = (char*)d_ws;
    auto alloc = [&p](size_t bytes) { char* q = p; p += (bytes + 63) & ~(size_t)63; return q; };
    short*    Hh      = (short*)alloc((size_t)n * CDIM * sizeof(short));
    unsigned* bufB    = (unsigned*)alloc((size_t)n * 64 * sizeof(unsigned));
    float*    alpha_s = (float*)alloc((size_t)n * sizeof(float));
    float*    alpha_d = (float*)alloc((size_t)n * sizeof(float));
    float*    bnsum   = (float*)alloc(512 * sizeof(float));
    short*    Wt1     = (short*)alloc(128 * 128 * sizeof(short));
    short*    Wt2     = (short*)alloc(128 * 128 * sizeof(short));
    short*    Wtc     = (short*)alloc(48 * 128 * sizeof(short));
    int*      bcurs   = (int*)alloc((size_t)NB * sizeof(int));
    int*      offs    = (int*)alloc((size_t)(n + 1) * sizeof(int));
    uint2*    bucket  = (uint2*)alloc((size_t)NB * BCAP * sizeof(uint2));
    int*      csr     = (int*)alloc((size_t)(E + n) * sizeof(int));

    // pkbuf/invb alias `bucket` (19.2 MB): bucket is dead after k_fillB and
    // rewritten by k_binA at the start of the next stream-ordered iteration.
    unsigned* pkbuf = (unsigned*)bucket;                 // (E+n)*4 = 6.8 MB
    float*    invb  = (float*)((char*)bucket + (((size_t)(E + n) * 4 + 63) & ~(size_t)63));

    k_setup<<<dim3(64), dim3(256), 0, stream>>>(bcurs, bnsum, NB, n, E, offs,
                                                W1, W2, Wc, Wt1, Wt2, Wtc);
    k_binA<<<dim3((E + 4095) / 4096), dim3(256), 0, stream>>>(src, dst, E, bcurs, bucket, NB);
    k_fillB<<<dim3(NB), dim3(256), 0, stream>>>(bucket, bcurs, n, NB, offs, csr);

    dim3 ggrid((n + 63) / 64);
    dim3 wgrid((n + 3) / 4);

    // layer 1
    k_gemm_mfma<<<ggrid, 256, 0, stream>>>(x, nullptr, Wt1, nullptr, nullptr, nullptr,
                                           invn, as1, ad1, Hh, alpha_s, alpha_d, n, 0);
    k_wts<<<wgrid, 256, 0, stream>>>(offs, csr, alpha_s, alpha_d, pkbuf, invb, n);
    k_gather<<<wgrid, 256, 0, stream>>>((const unsigned*)Hh, offs, pkbuf, invb, b1, bufB, n);
    k_bnstats<<<dim3(256), dim3(256), 0, stream>>>(bufB, n, bnsum);

    // layer 2 (BN1+relu from raw sums inside GEMM2 staging, bf16 input)
    k_gemm_mfma<<<ggrid, 256, 0, stream>>>(nullptr, bufB, Wt2, bnsum, g1, be1,
                                           invn, as2, ad2, Hh, alpha_s, alpha_d, n, 1);
    k_wts<<<wgrid, 256, 0, stream>>>(offs, csr, alpha_s, alpha_d, pkbuf, invb, n);
    k_gather<<<wgrid, 256, 0, stream>>>((const unsigned*)Hh, offs, pkbuf, invb, b2, bufB, n);
    k_bnstats<<<dim3(256), dim3(256), 0, stream>>>(bufB, n, bnsum + 256);

    // classifier (MFMA, BN2+relu fused in staging)
    k_cls<<<ggrid, 256, 0, stream>>>(bufB, Wtc, bc, bnsum + 256, g2, be2, invn, out, n);
}

// Round 4
// 443.524 us; speedup vs baseline: 1.0832x; 1.0832x over previous
//
#include <hip/hip_runtime.h>
#include <hip/hip_fp16.h>
#include <math.h>

// GAT 2-layer + BN + classifier, MI355X.
// R14 = R13 with the ds_bpermute addressing bug fixed: source lane for
// quad-batch b, quarter q is (4b+q), so addr = b*16 + (q<<2). R13 used
// b*16 + (q<<4) (non-injective -> duplicated/dropped edges).
// Structure: merged k_agg, quad-row gathers (one global_load_dwordx4 per
// 4 edges, 16 lanes x 16B per row), packed (src<<15)|fp16w broadcast via
// ds_bpermute, depth-8 issue (32 edges in flight), serial tail deg>32.

#define CDIM 128
#define NCLS_ 40
#define NEG_SLOPE_ 0.2f
#define BN_EPS_ 1e-5f
#define BRNG 256        // nodes per bucket (power of 2)
#define BCAP 6144       // max edges per bucket (mean 4096)
#define EPB 16          // edges per thread in k_binA (4096 per block)

using short8  = __attribute__((ext_vector_type(8))) short;
using short4v = __attribute__((ext_vector_type(4))) short;
using f32x4   = __attribute__((ext_vector_type(4))) float;

static __device__ __forceinline__ float lrelu(float a) {
    return a > 0.f ? a : NEG_SLOPE_ * a;
}
// fp32 -> bf16 round-to-nearest-even
static __device__ __forceinline__ short f2bf(float f) {
    unsigned u = __float_as_uint(f);
    u += 0x7fffu + ((u >> 16) & 1u);
    return (short)(u >> 16);
}
static __device__ __forceinline__ float bf_lo(unsigned u) { return __uint_as_float(u << 16); }
static __device__ __forceinline__ float bf_hi(unsigned u) { return __uint_as_float(u & 0xffff0000u); }
static __device__ __forceinline__ __half2 u2h2(unsigned u) { return __builtin_bit_cast(__half2, u); }
// add lane-xor-swapped copy (cross-quarter reduction)
static __device__ __forceinline__ __half2 h2xadd(__half2 x, int mask) {
    int o = __shfl_xor(__builtin_bit_cast(int, x), mask);
    return __hadd2(x, __builtin_bit_cast(__half2, o));
}

// ---------------- setup: cursors=0, bn sums=0, offs[n], W->bf16^T ----------
__global__ void k_setup(int* bcur, float* bnsum, int NB, int n, int E, int* offs,
                        const float* __restrict__ W1, const float* __restrict__ W2,
                        const float* __restrict__ Wc,
                        short* __restrict__ Wt1, short* __restrict__ Wt2,
                        short* __restrict__ Wtc) {
    int i = blockIdx.x * blockDim.x + threadIdx.x;
    if (i < NB) bcur[i] = 0;
    if (i < 512) bnsum[i] = 0.f;
    if (i == 0) offs[n] = E + n;
    if (i < 128 * 128) {
        int k = i >> 7, nn = i & 127;
        Wt1[nn * 128 + k] = f2bf(W1[i]);
        Wt2[nn * 128 + k] = f2bf(W2[i]);
    }
    if (i < 48 * 128) {             // padded bf16 Wc^T [48][128]
        int nn = i >> 7, k = i & 127;
        Wtc[i] = (nn < NCLS_) ? f2bf(Wc[k * NCLS_ + nn]) : (short)0;
    }
}

// ---------------- two-level binning into dst-range buckets -----------------
__global__ __launch_bounds__(256) void k_binA(
    const int* __restrict__ src, const int* __restrict__ dst, int E,
    int* __restrict__ bcur, uint2* __restrict__ bucket, int NB)
{
    __shared__ int hist[400];
    __shared__ int base[400];
    int t = threadIdx.x;
    long e0 = (long)blockIdx.x * (256 * EPB) + t;

    for (int i = t; i < NB; i += 256) hist[i] = 0;
    __syncthreads();

    int sv[EPB], dv[EPB];
    #pragma unroll
    for (int i = 0; i < EPB; i++) {
        long e = e0 + (long)i * 256;
        if (e < E) {
            sv[i] = src[e]; dv[i] = dst[e];
            atomicAdd(&hist[dv[i] >> 8], 1);
        } else dv[i] = -1;
    }
    __syncthreads();

    for (int i = t; i < NB; i += 256) {
        int h = hist[i];
        base[i] = (h > 0) ? atomicAdd(&bcur[i], h) : 0;
    }
    __syncthreads();
    for (int i = t; i < NB; i += 256) hist[i] = 0;   // reuse as cursor
    __syncthreads();

    #pragma unroll
    for (int i = 0; i < EPB; i++) {
        if (dv[i] >= 0) {
            int b = dv[i] >> 8;
            int pos = base[b] + atomicAdd(&hist[b], 1);
            if (pos < BCAP)
                bucket[(size_t)b * BCAP + pos] =
                    make_uint2((unsigned)sv[i], (unsigned)dv[i]);
        }
    }
}

// ---------------- per-bucket CSR build in LDS ------------------------------
__global__ __launch_bounds__(256) void k_fillB(
    const uint2* __restrict__ bucket, const int* __restrict__ bcur,
    int n, int NB, int* __restrict__ offs, int* __restrict__ csr)
{
    __shared__ int hist[256];
    __shared__ int scanb[256];
    __shared__ int cur[256];
    __shared__ int buf[BCAP + BRNG];
    int b = blockIdx.x, t = threadIdx.x;
    int node0 = b << 8;
    int nodesIn = min(BRNG, n - node0);
    int cnt = min(bcur[b], BCAP);
    const uint2* mybkt = bucket + (size_t)b * BCAP;

    int part = 0;
    for (int j = t; j < b; j += 256) part += min(bcur[j], BCAP);
    scanb[t] = part; __syncthreads();
    for (int s2 = 128; s2 > 0; s2 >>= 1) {
        if (t < s2) scanb[t] += scanb[t + s2];
        __syncthreads();
    }
    int base = scanb[0] + node0;
    __syncthreads();

    hist[t] = 0; __syncthreads();
    for (int e2 = t; e2 < cnt; e2 += 256)
        atomicAdd(&hist[mybkt[e2].y & 255], 1);
    __syncthreads();

    int v = hist[t] + ((t < nodesIn) ? 1 : 0);
    scanb[t] = v; __syncthreads();
    for (int d = 1; d < 256; d <<= 1) {
        int x2 = (t >= d) ? scanb[t - d] : 0;
        __syncthreads();
        scanb[t] += x2;
        __syncthreads();
    }
    int lo = scanb[t] - v;
    if (t < nodesIn) {
        offs[node0 + t] = base + lo;
        buf[lo] = node0 + t;          // self-loop occupies slot 0
        cur[t] = lo + 1;
    }
    __syncthreads();

    for (int e2 = t; e2 < cnt; e2 += 256) {
        uint2 ed = mybkt[e2];
        int pos = atomicAdd(&cur[ed.y & 255], 1);
        buf[pos] = (int)ed.x;
    }
    __syncthreads();

    int tot = cnt + nodesIn;
    for (int j2 = t; j2 < tot; j2 += 256) csr[base + j2] = buf[j2];
}

// ---------------- MFMA GEMM: Hh(f16) = act(X) @ W, alpha fused -------------
__global__ __launch_bounds__(256) void k_gemm_mfma(
    const float* __restrict__ Xf, const unsigned* __restrict__ Xb,
    const short* __restrict__ Wt,
    const float* __restrict__ bnsum, const float* __restrict__ gamma,
    const float* __restrict__ beta, float invn,
    const float* __restrict__ av_s, const float* __restrict__ av_d,
    short* __restrict__ Hh, float* __restrict__ alpha_s, float* __restrict__ alpha_d,
    int n, int fuse)
{
    __shared__ short As[64 * 128];    // 16.4 KB (reused as H transpose buffer)
    __shared__ short Bs[128 * 128];   // 32.8 KB
    __shared__ float part_s[4][64];
    __shared__ float part_d[4][64];
    int t = threadIdx.x;
    int row0 = blockIdx.x * 64;

    for (int j = 0; j < 8; j++) {
        int idx = j * 256 + t;
        int nn = idx >> 4, cc = idx & 15;
        *(short8*)(Bs + nn * 128 + cc * 8) = *(const short8*)(Wt + nn * 128 + cc * 8);
    }
    float4 sc4 = make_float4(1.f, 1.f, 1.f, 1.f);
    float4 sh4 = make_float4(0.f, 0.f, 0.f, 0.f);
    if (fuse) {
        int cb = (t & 31) * 4;
        float4 s0 = *(const float4*)(bnsum + cb);
        float4 s1 = *(const float4*)(bnsum + 128 + cb);
        float4 gm = *(const float4*)(gamma + cb);
        float4 bt = *(const float4*)(beta + cb);
        float mean, var;
        mean = s0.x * invn; var = fmaxf(s1.x * invn - mean * mean, 0.f);
        sc4.x = gm.x * rsqrtf(var + BN_EPS_); sh4.x = bt.x - mean * sc4.x;
        mean = s0.y * invn; var = fmaxf(s1.y * invn - mean * mean, 0.f);
        sc4.y = gm.y * rsqrtf(var + BN_EPS_); sh4.y = bt.y - mean * sc4.y;
        mean = s0.z * invn; var = fmaxf(s1.z * invn - mean * mean, 0.f);
        sc4.z = gm.z * rsqrtf(var + BN_EPS_); sh4.z = bt.z - mean * sc4.z;
        mean = s0.w * invn; var = fmaxf(s1.w * invn - mean * mean, 0.f);
        sc4.w = gm.w * rsqrtf(var + BN_EPS_); sh4.w = bt.w - mean * sc4.w;
    }
    for (int j = 0; j < 8; j++) {
        int idx = j * 256 + t;
        int r = idx >> 5, k4 = idx & 31;
        int gr = row0 + r;
        float4 xv = make_float4(0.f, 0.f, 0.f, 0.f);
        if (fuse) {
            if (gr < n) {
                uint2 u = *(const uint2*)(Xb + (size_t)gr * 64 + k4 * 2);
                xv.x = bf_lo(u.x); xv.y = bf_hi(u.x);
                xv.z = bf_lo(u.y); xv.w = bf_hi(u.y);
            }
            xv.x = fmaxf(fmaf(xv.x, sc4.x, sh4.x), 0.f);
            xv.y = fmaxf(fmaf(xv.y, sc4.y, sh4.y), 0.f);
            xv.z = fmaxf(fmaf(xv.z, sc4.z, sh4.z), 0.f);
            xv.w = fmaxf(fmaf(xv.w, sc4.w, sh4.w), 0.f);
        } else {
            if (gr < n) xv = *(const float4*)(Xf + (size_t)gr * CDIM + k4 * 4);
        }
        short4v o;
        o.x = f2bf(xv.x); o.y = f2bf(xv.y); o.z = f2bf(xv.z); o.w = f2bf(xv.w);
        *(short4v*)(As + r * 128 + k4 * 4) = o;
    }
    __syncthreads();

    int w = t >> 6, lane = t & 63, q = lane >> 4, c = lane & 15;
    f32x4 zero = {0.f, 0.f, 0.f, 0.f};
    f32x4 acc[4][2];
    for (int i = 0; i < 4; i++) { acc[i][0] = zero; acc[i][1] = zero; }

    for (int ks = 0; ks < 4; ks++) {
        int k0 = ks * 32 + q * 8;
        short8 a0 = *(short8*)(As + (c) * 128 + k0);
        short8 a1 = *(short8*)(As + (16 + c) * 128 + k0);
        short8 a2 = *(short8*)(As + (32 + c) * 128 + k0);
        short8 a3 = *(short8*)(As + (48 + c) * 128 + k0);
        short8 b0 = *(short8*)(Bs + (w * 32 + c) * 128 + k0);
        short8 b1 = *(short8*)(Bs + (w * 32 + 16 + c) * 128 + k0);
        acc[0][0] = __builtin_amdgcn_mfma_f32_16x16x32_bf16(a0, b0, acc[0][0], 0, 0, 0);
        acc[1][0] = __builtin_amdgcn_mfma_f32_16x16x32_bf16(a1, b0, acc[1][0], 0, 0, 0);
        acc[2][0] = __builtin_amdgcn_mfma_f32_16x16x32_bf16(a2, b0, acc[2][0], 0, 0, 0);
        acc[3][0] = __builtin_amdgcn_mfma_f32_16x16x32_bf16(a3, b0, acc[3][0], 0, 0, 0);
        acc[0][1] = __builtin_amdgcn_mfma_f32_16x16x32_bf16(a0, b1, acc[0][1], 0, 0, 0);
        acc[1][1] = __builtin_amdgcn_mfma_f32_16x16x32_bf16(a1, b1, acc[1][1], 0, 0, 0);
        acc[2][1] = __builtin_amdgcn_mfma_f32_16x16x32_bf16(a2, b1, acc[2][1], 0, 0, 0);
        acc[3][1] = __builtin_amdgcn_mfma_f32_16x16x32_bf16(a3, b1, acc[3][1], 0, 0, 0);
    }

    float as0 = av_s[w * 32 + c],      as1 = av_s[w * 32 + 16 + c];
    float ad0 = av_d[w * 32 + c],      ad1 = av_d[w * 32 + 16 + c];
    #pragma unroll
    for (int mt = 0; mt < 4; mt++) {
        #pragma unroll
        for (int r = 0; r < 4; r++) {
            float v0 = acc[mt][0][r], v1 = acc[mt][1][r];
            float ps = v0 * as0 + v1 * as1;
            float pd = v0 * ad0 + v1 * ad1;
            #pragma unroll
            for (int off = 1; off < 16; off <<= 1) {
                ps += __shfl_xor(ps, off);
                pd += __shfl_xor(pd, off);
            }
            if (c == 0) {
                part_s[w][mt * 16 + q * 4 + r] = ps;
                part_d[w][mt * 16 + q * 4 + r] = pd;
            }
        }
    }
    __syncthreads();

    // transpose H as packed fp16 (consumed only by k_agg's __hfma2 path)
    short* Hs = As;
    #pragma unroll
    for (int mt = 0; mt < 4; mt++)
        #pragma unroll
        for (int nt = 0; nt < 2; nt++)
            #pragma unroll
            for (int r = 0; r < 4; r++)
                Hs[(mt * 16 + q * 4 + r) * 128 + w * 32 + nt * 16 + c] =
                    (short)__half_as_ushort(__float2half_rn(acc[mt][nt][r]));

    if (t < 64) {
        int row = row0 + t;
        if (row < n) {
            alpha_s[row] = part_s[0][t] + part_s[1][t] + part_s[2][t] + part_s[3][t];
            alpha_d[row] = part_d[0][t] + part_d[1][t] + part_d[2][t] + part_d[3][t];
        }
    }
    __syncthreads();

    for (int j = 0; j < 4; j++) {
        int idx = j * 256 + t;
        int r = idx >> 4, cc = idx & 15;
        int gr = row0 + r;
        if (gr < n)
            *(short8*)(Hh + (size_t)gr * 128 + cc * 8) = *(short8*)(Hs + r * 128 + cc * 8);
    }
}

// ---------------- ONE-PASS softmax + quad-row aggregation ------------------
// One wave per node. Per chunk of <=64 edges: lane-parallel softmax, pack
// (src<<15)|fp16w in-register, then gather 4 rows per global_load_dwordx4
// (quarter-wave per row, 16 lanes x 16B). ds_bpermute broadcasts the packed
// word: quad-batch b, quarter q pulls source lane 4b+q (addr = b*16 + q*4).
__global__ __launch_bounds__(256) void k_agg(
    const unsigned* __restrict__ Hh, const int* __restrict__ offs,
    const int* __restrict__ csr, const float* __restrict__ alpha_s,
    const float* __restrict__ alpha_d, const float* __restrict__ bias,
    unsigned* __restrict__ Ob, int n)
{
    int i = blockIdx.x * 4 + (threadIdx.x >> 6);
    int lane = threadIdx.x & 63;
    if (i >= n) return;
    int o0 = offs[i], o1 = offs[i + 1];
    float adi = alpha_d[i];
    int sl = lane & 15;              // sublane within quarter
    int qa = (lane >> 4) << 2;       // quarter id * 4 bytes (bperm addr part)
    const uint4* H4 = (const uint4*)Hh;   // 16B granules: row*16 + sl

    __half2 a0h = u2h2(0), a1h = u2h2(0), a2h = u2h2(0), a3h = u2h2(0);
    float m = -1e30f, se = 0.f;

    for (int c0 = o0; c0 < o1; c0 += 64) {
        int j = c0 + lane;
        int cnt = min(64, o1 - c0);
        bool v = j < o1;
        int sj = v ? csr[j] : 0;
        float a = v ? lrelu(alpha_s[sj] + adi) : -1e30f;

        float cm = a;
        #pragma unroll
        for (int o = 32; o > 0; o >>= 1) cm = fmaxf(cm, __shfl_xor(cm, o));
        if (cm > m) {                 // wave-uniform branch
            float r = __expf(m - cm);
            se *= r;
            __half2 r2 = __float2half2_rn(r);
            a0h = __hmul2(a0h, r2); a1h = __hmul2(a1h, r2);
            a2h = __hmul2(a2h, r2); a3h = __hmul2(a3h, r2);
            m = cm;
        }
        float wl = v ? __expf(a - m) : 0.f;
        se += wl;
        unsigned pk = ((unsigned)sj << 15) |
                      (unsigned)__half_as_ushort(__float2half_rn(wl));

        int nb = (cnt + 3) >> 2;      // 1..16 quad-batches, wave-uniform
        uint4 dat[8]; unsigned pkv[8];
        #pragma unroll
        for (int b = 0; b < 8; b++) {
            if (b < nb) {
                pkv[b] = (unsigned)__builtin_amdgcn_ds_bpermute(b * 16 + qa, (int)pk);
                dat[b] = H4[(pkv[b] >> 15) * 16u + (unsigned)sl];
            }
        }
        #pragma unroll
        for (int b = 0; b < 8; b++) {
            if (b < nb) {
                unsigned hw = pkv[b] & 0x7fffu; hw |= hw << 16;
                __half2 w2 = u2h2(hw);
                a0h = __hfma2(u2h2(dat[b].x), w2, a0h);
                a1h = __hfma2(u2h2(dat[b].y), w2, a1h);
                a2h = __hfma2(u2h2(dat[b].z), w2, a2h);
                a3h = __hfma2(u2h2(dat[b].w), w2, a3h);
            }
        }
        for (int b = 8; b < nb; b++) {   // rare: deg>32 within chunk
            unsigned pv = (unsigned)__builtin_amdgcn_ds_bpermute(b * 16 + qa, (int)pk);
            uint4 d = H4[(pv >> 15) * 16u + (unsigned)sl];
            unsigned hw = pv & 0x7fffu; hw |= hw << 16;
            __half2 w2 = u2h2(hw);
            a0h = __hfma2(u2h2(d.x), w2, a0h);
            a1h = __hfma2(u2h2(d.y), w2, a1h);
            a2h = __hfma2(u2h2(d.z), w2, a2h);
            a3h = __hfma2(u2h2(d.w), w2, a3h);
        }
    }

    #pragma unroll
    for (int o = 32; o > 0; o >>= 1) se += __shfl_xor(se, o);
    float inv = 1.f / se;

    // cross-quarter reduce: quarters hold disjoint edge subsets of the
    // same channels; sum over lane^32 then lane^16.
    a0h = h2xadd(a0h, 32); a1h = h2xadd(a1h, 32);
    a2h = h2xadd(a2h, 32); a3h = h2xadd(a3h, 32);
    a0h = h2xadd(a0h, 16); a1h = h2xadd(a1h, 16);
    a2h = h2xadd(a2h, 16); a3h = h2xadd(a3h, 16);

    if (lane < 16) {
        // lane sl holds channels 8*sl .. 8*sl+7 (4 half2 pairs)
        float2 bb0 = *(const float2*)(bias + sl * 8 + 0);
        float2 bb1 = *(const float2*)(bias + sl * 8 + 2);
        float2 bb2 = *(const float2*)(bias + sl * 8 + 4);
        float2 bb3 = *(const float2*)(bias + sl * 8 + 6);
        float2 f0 = __half22float2(a0h), f1 = __half22float2(a1h);
        float2 f2 = __half22float2(a2h), f3 = __half22float2(a3h);
        uint4 o4;
        {
            float rx = fmaf(f0.x, inv, bb0.x), ry = fmaf(f0.y, inv, bb0.y);
            o4.x = ((unsigned)(unsigned short)f2bf(ry) << 16) |
                   (unsigned)(unsigned short)f2bf(rx);
        }
        {
            float rx = fmaf(f1.x, inv, bb1.x), ry = fmaf(f1.y, inv, bb1.y);
            o4.y = ((unsigned)(unsigned short)f2bf(ry) << 16) |
                   (unsigned)(unsigned short)f2bf(rx);
        }
        {
            float rx = fmaf(f2.x, inv, bb2.x), ry = fmaf(f2.y, inv, bb2.y);
            o4.z = ((unsigned)(unsigned short)f2bf(ry) << 16) |
                   (unsigned)(unsigned short)f2bf(rx);
        }
        {
            float rx = fmaf(f3.x, inv, bb3.x), ry = fmaf(f3.y, inv, bb3.y);
            o4.w = ((unsigned)(unsigned short)f2bf(ry) << 16) |
                   (unsigned)(unsigned short)f2bf(rx);
        }
        *(uint4*)(Ob + (size_t)i * 64 + sl * 4) = o4;
    }
}

// ---------------- BN stats from packed bf16: per-channel sum / sumsq -------
__global__ void k_bnstats(const unsigned* __restrict__ Hb, int n, float* __restrict__ sums) {
    __shared__ float red[4][64][4];
    int w = threadIdx.x & 63;
    int g = threadIdx.x >> 6;
    float slo = 0.f, shi = 0.f, qlo = 0.f, qhi = 0.f;
    for (int r = blockIdx.x * 4 + g; r < n; r += gridDim.x * 4) {
        unsigned u = Hb[(size_t)r * 64 + w];
        float lo = bf_lo(u), hi = bf_hi(u);
        slo += lo; shi += hi; qlo += lo * lo; qhi += hi * hi;
    }
    red[g][w][0] = slo; red[g][w][1] = shi; red[g][w][2] = qlo; red[g][w][3] = qhi;
    __syncthreads();
    if (threadIdx.x < 64) {
        int w2 = threadIdx.x;
        float s0 = 0.f, s1 = 0.f, s2 = 0.f, s3 = 0.f;
        for (int gg = 0; gg < 4; gg++) {
            s0 += red[gg][w2][0]; s1 += red[gg][w2][1];
            s2 += red[gg][w2][2]; s3 += red[gg][w2][3];
        }
        atomicAdd(&sums[2 * w2], s0);
        atomicAdd(&sums[2 * w2 + 1], s1);
        atomicAdd(&sums[128 + 2 * w2], s2);
        atomicAdd(&sums[128 + 2 * w2 + 1], s3);
    }
}

// ---------------- classifier (MFMA): out = relu(bn(G)) @ Wc + bc -----------
__global__ __launch_bounds__(256) void k_cls(
    const unsigned* __restrict__ G, const short* __restrict__ Wtc,
    const float* __restrict__ bc, const float* __restrict__ bnsum,
    const float* __restrict__ gamma, const float* __restrict__ beta, float invn,
    float* __restrict__ out, int n)
{
    __shared__ short As[64 * 128];   // 16.4 KB
    __shared__ short Bs[48 * 128];   // 12.3 KB
    int t = threadIdx.x;
    int row0 = blockIdx.x * 64;

    for (int j = 0; j < 3; j++) {
        int idx = j * 256 + t;       // 768 short8 = 6144 shorts
        *(short8*)(Bs + idx * 8) = *(const short8*)(Wtc + idx * 8);
    }
    float4 sc4, sh4;
    {
        int cb = (t & 31) * 4;
        float4 s0 = *(const float4*)(bnsum + cb);
        float4 s1 = *(const float4*)(bnsum + 128 + cb);
        float4 gm = *(const float4*)(gamma + cb);
        float4 bt = *(const float4*)(beta + cb);
        float mean, var;
        mean = s0.x * invn; var = fmaxf(s1.x * invn - mean * mean, 0.f);
        sc4.x = gm.x * rsqrtf(var + BN_EPS_); sh4.x = bt.x - mean * sc4.x;
        mean = s0.y * invn; var = fmaxf(s1.y * invn - mean * mean, 0.f);
        sc4.y = gm.y * rsqrtf(var + BN_EPS_); sh4.y = bt.y - mean * sc4.y;
        mean = s0.z * invn; var = fmaxf(s1.z * invn - mean * mean, 0.f);
        sc4.z = gm.z * rsqrtf(var + BN_EPS_); sh4.z = bt.z - mean * sc4.z;
        mean = s0.w * invn; var = fmaxf(s1.w * invn - mean * mean, 0.f);
        sc4.w = gm.w * rsqrtf(var + BN_EPS_); sh4.w = bt.w - mean * sc4.w;
    }
    for (int j = 0; j < 8; j++) {
        int idx = j * 256 + t;
        int r = idx >> 5, k4 = idx & 31;
        int gr = row0 + r;
        float4 xv = make_float4(0.f, 0.f, 0.f, 0.f);
        if (gr < n) {
            uint2 u = *(const uint2*)(G + (size_t)gr * 64 + k4 * 2);
            xv.x = bf_lo(u.x); xv.y = bf_hi(u.x);
            xv.z = bf_lo(u.y); xv.w = bf_hi(u.y);
        }
        xv.x = fmaxf(fmaf(xv.x, sc4.x, sh4.x), 0.f);
        xv.y = fmaxf(fmaf(xv.y, sc4.y, sh4.y), 0.f);
        xv.z = fmaxf(fmaf(xv.z, sc4.z, sh4.z), 0.f);
        xv.w = fmaxf(fmaf(xv.w, sc4.w, sh4.w), 0.f);
        short4v o;
        o.x = f2bf(xv.x); o.y = f2bf(xv.y); o.z = f2bf(xv.z); o.w = f2bf(xv.w);
        *(short4v*)(As + r * 128 + k4 * 4) = o;
    }
    __syncthreads();

    int w = t >> 6, lane = t & 63, q = lane >> 4, c = lane & 15;
    f32x4 zero = {0.f, 0.f, 0.f, 0.f};
    f32x4 acc[3] = {zero, zero, zero};
    for (int ks = 0; ks < 4; ks++) {
        int k0 = ks * 32 + q * 8;
        short8 a  = *(short8*)(As + (w * 16 + c) * 128 + k0);
        short8 b0 = *(short8*)(Bs + (c) * 128 + k0);
        short8 b1 = *(short8*)(Bs + (16 + c) * 128 + k0);
        short8 b2 = *(short8*)(Bs + (32 + c) * 128 + k0);
        acc[0] = __builtin_amdgcn_mfma_f32_16x16x32_bf16(a, b0, acc[0], 0, 0, 0);
        acc[1] = __builtin_amdgcn_mfma_f32_16x16x32_bf16(a, b1, acc[1], 0, 0, 0);
        acc[2] = __builtin_amdgcn_mfma_f32_16x16x32_bf16(a, b2, acc[2], 0, 0, 0);
    }
    float bc0 = bc[c], bc1 = bc[16 + c], bc2 = (c < 8) ? bc[32 + c] : 0.f;
    #pragma unroll
    for (int r = 0; r < 4; r++) {
        int row = row0 + w * 16 + q * 4 + r;
        if (row < n) {
            out[(size_t)row * NCLS_ + c]      = acc[0][r] + bc0;
            out[(size_t)row * NCLS_ + 16 + c] = acc[1][r] + bc1;
            if (c < 8) out[(size_t)row * NCLS_ + 32 + c] = acc[2][r] + bc2;
        }
    }
}

// ---------------- launch ---------------------------------------------------
extern "C" void kernel_launch(void* const* d_in, const int* in_sizes, int n_in,
                              void* d_out, int out_size, void* d_ws, size_t ws_size,
                              hipStream_t stream)
{
    const float* x   = (const float*)d_in[0];
    const int*   ei  = (const int*)d_in[1];
    const float* W1  = (const float*)d_in[2];
    const float* as1 = (const float*)d_in[3];
    const float* ad1 = (const float*)d_in[4];
    const float* b1  = (const float*)d_in[5];
    const float* g1  = (const float*)d_in[6];
    const float* be1 = (const float*)d_in[7];
    const float* W2  = (const float*)d_in[8];
    const float* as2 = (const float*)d_in[9];
    const float* ad2 = (const float*)d_in[10];
    const float* b2  = (const float*)d_in[11];
    const float* g2  = (const float*)d_in[12];
    const float* be2 = (const float*)d_in[13];
    const float* Wc  = (const float*)d_in[14];
    const float* bc  = (const float*)d_in[15];
    float* out = (float*)d_out;

    int n = in_sizes[0] / CDIM;     // 100000
    int E = in_sizes[1] / 2;        // 1600000
    const int* src = ei;
    const int* dst = ei + E;
    float invn = 1.f / (float)n;
    int NB = (n + BRNG - 1) / BRNG; // 391

    // workspace layout (64B-aligned chunks)
    char* p = (char*)d_ws;
    auto alloc = [&p](size_t bytes) { char* q = p; p += (bytes + 63) & ~(size_t)63; return q; };
    short*    Hh      = (short*)alloc((size_t)n * CDIM * sizeof(short));
    unsigned* bufB    = (unsigned*)alloc((size_t)n * 64 * sizeof(unsigned));
    float*    alpha_s = (float*)alloc((size_t)n * sizeof(float));
    float*    alpha_d = (float*)alloc((size_t)n * sizeof(float));
    float*    bnsum   = (float*)alloc(512 * sizeof(float));
    short*    Wt1     = (short*)alloc(128 * 128 * sizeof(short));
    short*    Wt2     = (short*)alloc(128 * 128 * sizeof(short));
    short*    Wtc     = (short*)alloc(48 * 128 * sizeof(short));
    int*      bcurs   = (int*)alloc((size_t)NB * sizeof(int));
    int*      offs    = (int*)alloc((size_t)(n + 1) * sizeof(int));
    uint2*    bucket  = (uint2*)alloc((size_t)NB * BCAP * sizeof(uint2));
    int*      csr     = (int*)alloc((size_t)(E + n) * sizeof(int));

    k_setup<<<dim3(64), dim3(256), 0, stream>>>(bcurs, bnsum, NB, n, E, offs,
                                                W1, W2, Wc, Wt1, Wt2, Wtc);
    k_binA<<<dim3((E + 4095) / 4096), dim3(256), 0, stream>>>(src, dst, E, bcurs, bucket, NB);
    k_fillB<<<dim3(NB), dim3(256), 0, stream>>>(bucket, bcurs, n, NB, offs, csr);

    dim3 ggrid((n + 63) / 64);
    dim3 wgrid((n + 3) / 4);

    // layer 1
    k_gemm_mfma<<<ggrid, 256, 0, stream>>>(x, nullptr, Wt1, nullptr, nullptr, nullptr,
                                           invn, as1, ad1, Hh, alpha_s, alpha_d, n, 0);
    k_agg<<<wgrid, 256, 0, stream>>>((const unsigned*)Hh, offs, csr, alpha_s, alpha_d,
                                     b1, bufB, n);
    k_bnstats<<<dim3(256), dim3(256), 0, stream>>>(bufB, n, bnsum);

    // layer 2 (BN1+relu from raw sums inside GEMM2 staging, bf16 input)
    k_gemm_mfma<<<ggrid, 256, 0, stream>>>(nullptr, bufB, Wt2, bnsum, g1, be1,
                                           invn, as2, ad2, Hh, alpha_s, alpha_d, n, 1);
    k_agg<<<wgrid, 256, 0, stream>>>((const unsigned*)Hh, offs, csr, alpha_s, alpha_d,
                                     b2, bufB, n);
    k_bnstats<<<dim3(256), dim3(256), 0, stream>>>(bufB, n, bnsum + 256);

    // classifier (MFMA, BN2+relu fused in staging)
    k_cls<<<ggrid, 256, 0, stream>>>(bufB, Wtc, bc, bnsum + 256, g2, be2, invn, out, n);
}

// Round 6
// 436.093 us; speedup vs baseline: 1.1017x; 1.0170x over previous
//
#include <hip/hip_runtime.h>
#include <hip/hip_fp16.h>
#include <math.h>

// GAT 2-layer + BN + classifier, MI355X.
// R16: k_agg = R11 exact (fp16 rows, readlane gather, depth-3 prefetch) --
// proven at its compulsory-fabric-traffic floor (~67us; FETCH ~= 8 XCD x
// 88% x 25.6MB table, invariant across R10-R14 structural variants; fp8
// payload failed accuracy in R15). New: alpha fused into the GEMM as an
// extra MFMA B-column pair (ws=W@a_s, wd=W@a_d precomputed in k_setup),
// removing the 128-shfl reduce + part-array LDS + one sync from k_gemm.

#define CDIM 128
#define NCLS_ 40
#define NEG_SLOPE_ 0.2f
#define BN_EPS_ 1e-5f
#define BRNG 256        // nodes per bucket (power of 2)
#define BCAP 6144       // max edges per bucket (mean 4096)
#define EPB 16          // edges per thread in k_binA (4096 per block)

using short8  = __attribute__((ext_vector_type(8))) short;
using short4v = __attribute__((ext_vector_type(4))) short;
using f32x4   = __attribute__((ext_vector_type(4))) float;

static __device__ __forceinline__ float lrelu(float a) {
    return a > 0.f ? a : NEG_SLOPE_ * a;
}
// fp32 -> bf16 round-to-nearest-even
static __device__ __forceinline__ short f2bf(float f) {
    unsigned u = __float_as_uint(f);
    u += 0x7fffu + ((u >> 16) & 1u);
    return (short)(u >> 16);
}
static __device__ __forceinline__ float bf_lo(unsigned u) { return __uint_as_float(u << 16); }
static __device__ __forceinline__ float bf_hi(unsigned u) { return __uint_as_float(u & 0xffff0000u); }
static __device__ __forceinline__ __half2 u2h2(unsigned u) { return __builtin_bit_cast(__half2, u); }
static __device__ __forceinline__ unsigned h22u(__half2 h) { return __builtin_bit_cast(unsigned, h); }

// ---------------- setup: cursors=0, bn sums=0, offs[n], W->bf16^T, ws/wd ---
__global__ void k_setup(int* bcur, float* bnsum, int NB, int n, int E, int* offs,
                        const float* __restrict__ W1, const float* __restrict__ W2,
                        const float* __restrict__ Wc,
                        const float* __restrict__ as1, const float* __restrict__ ad1,
                        const float* __restrict__ as2, const float* __restrict__ ad2,
                        short* __restrict__ Wt1, short* __restrict__ Wt2,
                        short* __restrict__ Wtc,
                        short* __restrict__ wsd1, short* __restrict__ wsd2) {
    int i = blockIdx.x * blockDim.x + threadIdx.x;
    if (i < NB) bcur[i] = 0;
    if (i < 512) bnsum[i] = 0.f;
    if (i == 0) offs[n] = E + n;
    if (i < 128 * 128) {
        int k = i >> 7, nn = i & 127;
        Wt1[nn * 128 + k] = f2bf(W1[i]);
        Wt2[nn * 128 + k] = f2bf(W2[i]);
    }
    if (i < 48 * 128) {             // padded bf16 Wc^T [48][128]
        int nn = i >> 7, k = i & 127;
        Wtc[i] = (nn < NCLS_) ? f2bf(Wc[k * NCLS_ + nn]) : (short)0;
    }
    if (i < 128) {                  // ws = W @ a_s, wd = W @ a_d (both layers)
        float s1 = 0.f, d1 = 0.f, s2 = 0.f, d2 = 0.f;
        for (int nn2 = 0; nn2 < 128; nn2++) {
            float w1v = W1[i * 128 + nn2], w2v = W2[i * 128 + nn2];
            s1 = fmaf(w1v, as1[nn2], s1); d1 = fmaf(w1v, ad1[nn2], d1);
            s2 = fmaf(w2v, as2[nn2], s2); d2 = fmaf(w2v, ad2[nn2], d2);
        }
        wsd1[i] = f2bf(s1); wsd1[128 + i] = f2bf(d1);
        wsd2[i] = f2bf(s2); wsd2[128 + i] = f2bf(d2);
    }
}

// ---------------- two-level binning into dst-range buckets -----------------
__global__ __launch_bounds__(256) void k_binA(
    const int* __restrict__ src, const int* __restrict__ dst, int E,
    int* __restrict__ bcur, uint2* __restrict__ bucket, int NB)
{
    __shared__ int hist[400];
    __shared__ int base[400];
    int t = threadIdx.x;
    long e0 = (long)blockIdx.x * (256 * EPB) + t;

    for (int i = t; i < NB; i += 256) hist[i] = 0;
    __syncthreads();

    int sv[EPB], dv[EPB];
    #pragma unroll
    for (int i = 0; i < EPB; i++) {
        long e = e0 + (long)i * 256;
        if (e < E) {
            sv[i] = src[e]; dv[i] = dst[e];
            atomicAdd(&hist[dv[i] >> 8], 1);
        } else dv[i] = -1;
    }
    __syncthreads();

    for (int i = t; i < NB; i += 256) {
        int h = hist[i];
        base[i] = (h > 0) ? atomicAdd(&bcur[i], h) : 0;
    }
    __syncthreads();
    for (int i = t; i < NB; i += 256) hist[i] = 0;   // reuse as cursor
    __syncthreads();

    #pragma unroll
    for (int i = 0; i < EPB; i++) {
        if (dv[i] >= 0) {
            int b = dv[i] >> 8;
            int pos = base[b] + atomicAdd(&hist[b], 1);
            if (pos < BCAP)
                bucket[(size_t)b * BCAP + pos] =
                    make_uint2((unsigned)sv[i], (unsigned)dv[i]);
        }
    }
}

// ---------------- per-bucket CSR build in LDS ------------------------------
__global__ __launch_bounds__(256) void k_fillB(
    const uint2* __restrict__ bucket, const int* __restrict__ bcur,
    int n, int NB, int* __restrict__ offs, int* __restrict__ csr)
{
    __shared__ int hist[256];
    __shared__ int scanb[256];
    __shared__ int cur[256];
    __shared__ int buf[BCAP + BRNG];
    int b = blockIdx.x, t = threadIdx.x;
    int node0 = b << 8;
    int nodesIn = min(BRNG, n - node0);
    int cnt = min(bcur[b], BCAP);
    const uint2* mybkt = bucket + (size_t)b * BCAP;

    int part = 0;
    for (int j = t; j < b; j += 256) part += min(bcur[j], BCAP);
    scanb[t] = part; __syncthreads();
    for (int s2 = 128; s2 > 0; s2 >>= 1) {
        if (t < s2) scanb[t] += scanb[t + s2];
        __syncthreads();
    }
    int base = scanb[0] + node0;
    __syncthreads();

    hist[t] = 0; __syncthreads();
    for (int e2 = t; e2 < cnt; e2 += 256)
        atomicAdd(&hist[mybkt[e2].y & 255], 1);
    __syncthreads();

    int v = hist[t] + ((t < nodesIn) ? 1 : 0);
    scanb[t] = v; __syncthreads();
    for (int d = 1; d < 256; d <<= 1) {
        int x2 = (t >= d) ? scanb[t - d] : 0;
        __syncthreads();
        scanb[t] += x2;
        __syncthreads();
    }
    int lo = scanb[t] - v;
    if (t < nodesIn) {
        offs[node0 + t] = base + lo;
        buf[lo] = node0 + t;          // self-loop occupies slot 0
        cur[t] = lo + 1;
    }
    __syncthreads();

    for (int e2 = t; e2 < cnt; e2 += 256) {
        uint2 ed = mybkt[e2];
        int pos = atomicAdd(&cur[ed.y & 255], 1);
        buf[pos] = (int)ed.x;
    }
    __syncthreads();

    int tot = cnt + nodesIn;
    for (int j2 = t; j2 < tot; j2 += 256) csr[base + j2] = buf[j2];
}

// ---------------- MFMA GEMM: Hh(f16) = act(X) @ W, alpha as B-columns ------
__global__ __launch_bounds__(256) void k_gemm_mfma(
    const float* __restrict__ Xf, const unsigned* __restrict__ Xb,
    const short* __restrict__ Wt, const short* __restrict__ wsd,
    const float* __restrict__ bnsum, const float* __restrict__ gamma,
    const float* __restrict__ beta, float invn,
    short* __restrict__ Hh, float* __restrict__ alpha_s, float* __restrict__ alpha_d,
    int n, int fuse)
{
    __shared__ short As[64 * 128];    // 16.4 KB (reused as H transpose buffer)
    __shared__ short Bs[128 * 128];   // 32.8 KB
    __shared__ short wl[256];         // ws (0..127), wd (128..255) bf16
    int t = threadIdx.x;
    int row0 = blockIdx.x * 64;

    for (int j = 0; j < 8; j++) {
        int idx = j * 256 + t;
        int nn = idx >> 4, cc = idx & 15;
        *(short8*)(Bs + nn * 128 + cc * 8) = *(const short8*)(Wt + nn * 128 + cc * 8);
    }
    if (t < 256) wl[t] = wsd[t];
    float4 sc4 = make_float4(1.f, 1.f, 1.f, 1.f);
    float4 sh4 = make_float4(0.f, 0.f, 0.f, 0.f);
    if (fuse) {
        int cb = (t & 31) * 4;
        float4 s0 = *(const float4*)(bnsum + cb);
        float4 s1 = *(const float4*)(bnsum + 128 + cb);
        float4 gm = *(const float4*)(gamma + cb);
        float4 bt = *(const float4*)(beta + cb);
        float mean, var;
        mean = s0.x * invn; var = fmaxf(s1.x * invn - mean * mean, 0.f);
        sc4.x = gm.x * rsqrtf(var + BN_EPS_); sh4.x = bt.x - mean * sc4.x;
        mean = s0.y * invn; var = fmaxf(s1.y * invn - mean * mean, 0.f);
        sc4.y = gm.y * rsqrtf(var + BN_EPS_); sh4.y = bt.y - mean * sc4.y;
        mean = s0.z * invn; var = fmaxf(s1.z * invn - mean * mean, 0.f);
        sc4.z = gm.z * rsqrtf(var + BN_EPS_); sh4.z = bt.z - mean * sc4.z;
        mean = s0.w * invn; var = fmaxf(s1.w * invn - mean * mean, 0.f);
        sc4.w = gm.w * rsqrtf(var + BN_EPS_); sh4.w = bt.w - mean * sc4.w;
    }
    for (int j = 0; j < 8; j++) {
        int idx = j * 256 + t;
        int r = idx >> 5, k4 = idx & 31;
        int gr = row0 + r;
        float4 xv = make_float4(0.f, 0.f, 0.f, 0.f);
        if (fuse) {
            if (gr < n) {
                uint2 u = *(const uint2*)(Xb + (size_t)gr * 64 + k4 * 2);
                xv.x = bf_lo(u.x); xv.y = bf_hi(u.x);
                xv.z = bf_lo(u.y); xv.w = bf_hi(u.y);
            }
            xv.x = fmaxf(fmaf(xv.x, sc4.x, sh4.x), 0.f);
            xv.y = fmaxf(fmaf(xv.y, sc4.y, sh4.y), 0.f);
            xv.z = fmaxf(fmaf(xv.z, sc4.z, sh4.z), 0.f);
            xv.w = fmaxf(fmaf(xv.w, sc4.w, sh4.w), 0.f);
        } else {
            if (gr < n) xv = *(const float4*)(Xf + (size_t)gr * CDIM + k4 * 4);
        }
        short4v o;
        o.x = f2bf(xv.x); o.y = f2bf(xv.y); o.z = f2bf(xv.z); o.w = f2bf(xv.w);
        *(short4v*)(As + r * 128 + k4 * 4) = o;
    }
    __syncthreads();

    int w = t >> 6, lane = t & 63, q = lane >> 4, c = lane & 15;
    f32x4 zero = {0.f, 0.f, 0.f, 0.f};
    f32x4 acc[4][2];
    f32x4 acc_a = zero;               // alpha: col0=alpha_s, col1=alpha_d
    for (int i = 0; i < 4; i++) { acc[i][0] = zero; acc[i][1] = zero; }

    for (int ks = 0; ks < 4; ks++) {
        int k0 = ks * 32 + q * 8;
        short8 a0 = *(short8*)(As + (c) * 128 + k0);
        short8 a1 = *(short8*)(As + (16 + c) * 128 + k0);
        short8 a2 = *(short8*)(As + (32 + c) * 128 + k0);
        short8 a3 = *(short8*)(As + (48 + c) * 128 + k0);
        short8 b0 = *(short8*)(Bs + (w * 32 + c) * 128 + k0);
        short8 b1 = *(short8*)(Bs + (w * 32 + 16 + c) * 128 + k0);
        acc[0][0] = __builtin_amdgcn_mfma_f32_16x16x32_bf16(a0, b0, acc[0][0], 0, 0, 0);
        acc[1][0] = __builtin_amdgcn_mfma_f32_16x16x32_bf16(a1, b0, acc[1][0], 0, 0, 0);
        acc[2][0] = __builtin_amdgcn_mfma_f32_16x16x32_bf16(a2, b0, acc[2][0], 0, 0, 0);
        acc[3][0] = __builtin_amdgcn_mfma_f32_16x16x32_bf16(a3, b0, acc[3][0], 0, 0, 0);
        acc[0][1] = __builtin_amdgcn_mfma_f32_16x16x32_bf16(a0, b1, acc[0][1], 0, 0, 0);
        acc[1][1] = __builtin_amdgcn_mfma_f32_16x16x32_bf16(a1, b1, acc[1][1], 0, 0, 0);
        acc[2][1] = __builtin_amdgcn_mfma_f32_16x16x32_bf16(a2, b1, acc[2][1], 0, 0, 0);
        acc[3][1] = __builtin_amdgcn_mfma_f32_16x16x32_bf16(a3, b1, acc[3][1], 0, 0, 0);

        // alpha columns: B col0 = ws, col1 = wd, rest 0; A = this wave's rows
        short8 ba;
        #pragma unroll
        for (int jj = 0; jj < 8; jj++) {
            short vs = wl[k0 + jj], vd = wl[128 + k0 + jj];
            ba[jj] = (c == 0) ? vs : ((c == 1) ? vd : (short)0);
        }
        short8 aw = (w == 0) ? a0 : ((w == 1) ? a1 : ((w == 2) ? a2 : a3));
        acc_a = __builtin_amdgcn_mfma_f32_16x16x32_bf16(aw, ba, acc_a, 0, 0, 0);
    }

    __syncthreads();                  // all As reads done before reuse

    // transpose H as packed fp16 (consumed only by k_agg's __hfma2 path)
    short* Hs = As;
    #pragma unroll
    for (int mt = 0; mt < 4; mt++)
        #pragma unroll
        for (int nt = 0; nt < 2; nt++)
            #pragma unroll
            for (int r = 0; r < 4; r++)
                Hs[(mt * 16 + q * 4 + r) * 128 + w * 32 + nt * 16 + c] =
                    (short)__half_as_ushort(__float2half_rn(acc[mt][nt][r]));

    // alpha store: wave w owns rows w*16 + q*4 + r; lane c==0 -> alpha_s,
    // c==1 -> alpha_d (D col = B col).
    if (c < 2) {
        #pragma unroll
        for (int r = 0; r < 4; r++) {
            int row = row0 + w * 16 + q * 4 + r;
            if (row < n) {
                if (c == 0) alpha_s[row] = acc_a[r];
                else        alpha_d[row] = acc_a[r];
            }
        }
    }
    __syncthreads();

    for (int j = 0; j < 4; j++) {
        int idx = j * 256 + t;
        int r = idx >> 4, cc = idx & 15;
        int gr = row0 + r;
        if (gr < n)
            *(short8*)(Hh + (size_t)gr * 128 + cc * 8) = *(short8*)(Hs + r * 128 + cc * 8);
    }
}

// ---------------- ONE-PASS softmax + aggregation (one wave per node) -------
// R11 exact: all <=24 row-gathers issued BEFORE the alpha gather + softmax
// (loads depend only on sj), 3-deep batch pipeline for degree>24.
__global__ __launch_bounds__(256) void k_agg(
    const unsigned* __restrict__ Hh, const int* __restrict__ offs,
    const int* __restrict__ csr, const float* __restrict__ alpha_s,
    const float* __restrict__ alpha_d, const float* __restrict__ bias,
    unsigned* __restrict__ Ob, int n)
{
    int i = blockIdx.x * 4 + (threadIdx.x >> 6);
    int lane = threadIdx.x & 63;
    if (i >= n) return;
    int o0 = offs[i], o1 = offs[i + 1];
    float adi = alpha_d[i];

    float m = -1e30f;
    float se = 0.f;
    __half2 acc2 = __floats2half2_rn(0.f, 0.f);

    for (int c0 = o0; c0 < o1; c0 += 64) {
        int j = c0 + lane;
        int cnt = min(64, o1 - c0);
        int sj = (j < o1) ? csr[j] : 0;   // invalid lanes -> row 0 (w=0)

        // ---- issue up to 24 H-row gathers now (independent of weights) ----
        unsigned ua[8], ub[8], uc[8];
        #pragma unroll
        for (int q = 0; q < 8; q++) {
            int s = __builtin_amdgcn_readlane(sj, q);
            ua[q] = Hh[(size_t)(unsigned)s * 64 + lane];
        }
        if (cnt > 8) {
            #pragma unroll
            for (int q = 0; q < 8; q++) {
                int s = __builtin_amdgcn_readlane(sj, 8 + q);
                ub[q] = Hh[(size_t)(unsigned)s * 64 + lane];
            }
        }
        if (cnt > 16) {
            #pragma unroll
            for (int q = 0; q < 8; q++) {
                int s = __builtin_amdgcn_readlane(sj, 16 + q);
                uc[q] = Hh[(size_t)(unsigned)s * 64 + lane];
            }
        }

        // ---- softmax weights (overlaps the in-flight gathers) ----
        float a = (j < o1) ? lrelu(alpha_s[sj] + adi) : -1e30f;
        float cm = a;
        #pragma unroll
        for (int o = 32; o > 0; o >>= 1) cm = fmaxf(cm, __shfl_xor(cm, o));
        if (cm > m) {
            float r = __expf(m - cm);
            se *= r;
            acc2 = __hmul2(acc2, __float2half2_rn(r));
            m = cm;
        }
        float wl2 = (j < o1) ? __expf(a - m) : 0.f;
        se += wl2;
        int wli = (int)h22u(__float2half2_rn(wl2));

        // ---- consume + prefetch, 24 edges per iteration ----
        for (int b = 0; b < cnt; b += 24) {
            #pragma unroll
            for (int q = 0; q < 8; q++) {
                int wq = __builtin_amdgcn_readlane(wli, b + q);
                acc2 = __hfma2(u2h2(ua[q]), u2h2((unsigned)wq), acc2);
            }
            if (b + 24 < cnt) {
                #pragma unroll
                for (int q = 0; q < 8; q++) {
                    int s = __builtin_amdgcn_readlane(sj, b + 24 + q);
                    ua[q] = Hh[(size_t)(unsigned)s * 64 + lane];
                }
            }
            if (b + 8 < cnt) {
                #pragma unroll
                for (int q = 0; q < 8; q++) {
                    int wq = __builtin_amdgcn_readlane(wli, b + 8 + q);
                    acc2 = __hfma2(u2h2(ub[q]), u2h2((unsigned)wq), acc2);
                }
                if (b + 32 < cnt) {
                    #pragma unroll
                    for (int q = 0; q < 8; q++) {
                        int s = __builtin_amdgcn_readlane(sj, b + 32 + q);
                        ub[q] = Hh[(size_t)(unsigned)s * 64 + lane];
                    }
                }
                if (b + 16 < cnt) {
                    #pragma unroll
                    for (int q = 0; q < 8; q++) {
                        int wq = __builtin_amdgcn_readlane(wli, b + 16 + q);
                        acc2 = __hfma2(u2h2(uc[q]), u2h2((unsigned)wq), acc2);
                    }
                    if (b + 40 < cnt) {
                        #pragma unroll
                        for (int q = 0; q < 8; q++) {
                            int s = __builtin_amdgcn_readlane(sj, b + 40 + q);
                            uc[q] = Hh[(size_t)(unsigned)s * 64 + lane];
                        }
                    }
                }
            }
        }
    }

    #pragma unroll
    for (int o = 32; o > 0; o >>= 1) se += __shfl_xor(se, o);
    float inv = 1.f / se;
    float2 af = __half22float2(acc2);
    float2 b2 = *(const float2*)(bias + lane * 2);
    float rx = fmaf(af.x, inv, b2.x);
    float ry = fmaf(af.y, inv, b2.y);
    unsigned pack = ((unsigned)(unsigned short)f2bf(ry) << 16) |
                    (unsigned)(unsigned short)f2bf(rx);
    Ob[(size_t)i * 64 + lane] = pack;
}

// ---------------- BN stats from packed bf16: per-channel sum / sumsq -------
__global__ void k_bnstats(const unsigned* __restrict__ Hb, int n, float* __restrict__ sums) {
    __shared__ float red[4][64][4];
    int w = threadIdx.x & 63;
    int g = threadIdx.x >> 6;
    float slo = 0.f, shi = 0.f, qlo = 0.f, qhi = 0.f;
    for (int r = blockIdx.x * 4 + g; r < n; r += gridDim.x * 4) {
        unsigned u = Hb[(size_t)r * 64 + w];
        float lo = bf_lo(u), hi = bf_hi(u);
        slo += lo; shi += hi; qlo += lo * lo; qhi += hi * hi;
    }
    red[g][w][0] = slo; red[g][w][1] = shi; red[g][w][2] = qlo; red[g][w][3] = qhi;
    __syncthreads();
    if (threadIdx.x < 64) {
        int w2 = threadIdx.x;
        float s0 = 0.f, s1 = 0.f, s2 = 0.f, s3 = 0.f;
        for (int gg = 0; gg < 4; gg++) {
            s0 += red[gg][w2][0]; s1 += red[gg][w2][1];
            s2 += red[gg][w2][2]; s3 += red[gg][w2][3];
        }
        atomicAdd(&sums[2 * w2], s0);
        atomicAdd(&sums[2 * w2 + 1], s1);
        atomicAdd(&sums[128 + 2 * w2], s2);
        atomicAdd(&sums[128 + 2 * w2 + 1], s3);
    }
}

// ---------------- classifier (MFMA): out = relu(bn(G)) @ Wc + bc -----------
__global__ __launch_bounds__(256) void k_cls(
    const unsigned* __restrict__ G, const short* __restrict__ Wtc,
    const float* __restrict__ bc, const float* __restrict__ bnsum,
    const float* __restrict__ gamma, const float* __restrict__ beta, float invn,
    float* __restrict__ out, int n)
{
    __shared__ short As[64 * 128];   // 16.4 KB
    __shared__ short Bs[48 * 128];   // 12.3 KB
    int t = threadIdx.x;
    int row0 = blockIdx.x * 64;

    for (int j = 0; j < 3; j++) {
        int idx = j * 256 + t;       // 768 short8 = 6144 shorts
        *(short8*)(Bs + idx * 8) = *(const short8*)(Wtc + idx * 8);
    }
    float4 sc4, sh4;
    {
        int cb = (t & 31) * 4;
        float4 s0 = *(const float4*)(bnsum + cb);
        float4 s1 = *(const float4*)(bnsum + 128 + cb);
        float4 gm = *(const float4*)(gamma + cb);
        float4 bt = *(const float4*)(beta + cb);
        float mean, var;
        mean = s0.x * invn; var = fmaxf(s1.x * invn - mean * mean, 0.f);
        sc4.x = gm.x * rsqrtf(var + BN_EPS_); sh4.x = bt.x - mean * sc4.x;
        mean = s0.y * invn; var = fmaxf(s1.y * invn - mean * mean, 0.f);
        sc4.y = gm.y * rsqrtf(var + BN_EPS_); sh4.y = bt.y - mean * sc4.y;
        mean = s0.z * invn; var = fmaxf(s1.z * invn - mean * mean, 0.f);
        sc4.z = gm.z * rsqrtf(var + BN_EPS_); sh4.z = bt.z - mean * sc4.z;
        mean = s0.w * invn; var = fmaxf(s1.w * invn - mean * mean, 0.f);
        sc4.w = gm.w * rsqrtf(var + BN_EPS_); sh4.w = bt.w - mean * sc4.w;
    }
    for (int j = 0; j < 8; j++) {
        int idx = j * 256 + t;
        int r = idx >> 5, k4 = idx & 31;
        int gr = row0 + r;
        float4 xv = make_float4(0.f, 0.f, 0.f, 0.f);
        if (gr < n) {
            uint2 u = *(const uint2*)(G + (size_t)gr * 64 + k4 * 2);
            xv.x = bf_lo(u.x); xv.y = bf_hi(u.x);
            xv.z = bf_lo(u.y); xv.w = bf_hi(u.y);
        }
        xv.x = fmaxf(fmaf(xv.x, sc4.x, sh4.x), 0.f);
        xv.y = fmaxf(fmaf(xv.y, sc4.y, sh4.y), 0.f);
        xv.z = fmaxf(fmaf(xv.z, sc4.z, sh4.z), 0.f);
        xv.w = fmaxf(fmaf(xv.w, sc4.w, sh4.w), 0.f);
        short4v o;
        o.x = f2bf(xv.x); o.y = f2bf(xv.y); o.z = f2bf(xv.z); o.w = f2bf(xv.w);
        *(short4v*)(As + r * 128 + k4 * 4) = o;
    }
    __syncthreads();

    int w = t >> 6, lane = t & 63, q = lane >> 4, c = lane & 15;
    f32x4 zero = {0.f, 0.f, 0.f, 0.f};
    f32x4 acc[3] = {zero, zero, zero};
    for (int ks = 0; ks < 4; ks++) {
        int k0 = ks * 32 + q * 8;
        short8 a  = *(short8*)(As + (w * 16 + c) * 128 + k0);
        short8 b0 = *(short8*)(Bs + (c) * 128 + k0);
        short8 b1 = *(short8*)(Bs + (16 + c) * 128 + k0);
        short8 b2 = *(short8*)(Bs + (32 + c) * 128 + k0);
        acc[0] = __builtin_amdgcn_mfma_f32_16x16x32_bf16(a, b0, acc[0], 0, 0, 0);
        acc[1] = __builtin_amdgcn_mfma_f32_16x16x32_bf16(a, b1, acc[1], 0, 0, 0);
        acc[2] = __builtin_amdgcn_mfma_f32_16x16x32_bf16(a, b2, acc[2], 0, 0, 0);
    }
    float bc0 = bc[c], bc1 = bc[16 + c], bc2 = (c < 8) ? bc[32 + c] : 0.f;
    #pragma unroll
    for (int r = 0; r < 4; r++) {
        int row = row0 + w * 16 + q * 4 + r;
        if (row < n) {
            out[(size_t)row * NCLS_ + c]      = acc[0][r] + bc0;
            out[(size_t)row * NCLS_ + 16 + c] = acc[1][r] + bc1;
            if (c < 8) out[(size_t)row * NCLS_ + 32 + c] = acc[2][r] + bc2;
        }
    }
}

// ---------------- launch ---------------------------------------------------
extern "C" void kernel_launch(void* const* d_in, const int* in_sizes, int n_in,
                              void* d_out, int out_size, void* d_ws, size_t ws_size,
                              hipStream_t stream)
{
    const float* x   = (const float*)d_in[0];
    const int*   ei  = (const int*)d_in[1];
    const float* W1  = (const float*)d_in[2];
    const float* as1 = (const float*)d_in[3];
    const float* ad1 = (const float*)d_in[4];
    const float* b1  = (const float*)d_in[5];
    const float* g1  = (const float*)d_in[6];
    const float* be1 = (const float*)d_in[7];
    const float* W2  = (const float*)d_in[8];
    const float* as2 = (const float*)d_in[9];
    const float* ad2 = (const float*)d_in[10];
    const float* b2  = (const float*)d_in[11];
    const float* g2  = (const float*)d_in[12];
    const float* be2 = (const float*)d_in[13];
    const float* Wc  = (const float*)d_in[14];
    const float* bc  = (const float*)d_in[15];
    float* out = (float*)d_out;

    int n = in_sizes[0] / CDIM;     // 100000
    int E = in_sizes[1] / 2;        // 1600000
    const int* src = ei;
    const int* dst = ei + E;
    float invn = 1.f / (float)n;
    int NB = (n + BRNG - 1) / BRNG; // 391

    // workspace layout (64B-aligned chunks)
    char* p = (char*)d_ws;
    auto alloc = [&p](size_t bytes) { char* q = p; p += (bytes + 63) & ~(size_t)63; return q; };
    short*    Hh      = (short*)alloc((size_t)n * CDIM * sizeof(short));
    unsigned* bufB    = (unsigned*)alloc((size_t)n * 64 * sizeof(unsigned));
    float*    alpha_s = (float*)alloc((size_t)n * sizeof(float));
    float*    alpha_d = (float*)alloc((size_t)n * sizeof(float));
    float*    bnsum   = (float*)alloc(512 * sizeof(float));
    short*    Wt1     = (short*)alloc(128 * 128 * sizeof(short));
    short*    Wt2     = (short*)alloc(128 * 128 * sizeof(short));
    short*    Wtc     = (short*)alloc(48 * 128 * sizeof(short));
    short*    wsd1    = (short*)alloc(256 * sizeof(short));
    short*    wsd2    = (short*)alloc(256 * sizeof(short));
    int*      bcurs   = (int*)alloc((size_t)NB * sizeof(int));
    int*      offs    = (int*)alloc((size_t)(n + 1) * sizeof(int));
    uint2*    bucket  = (uint2*)alloc((size_t)NB * BCAP * sizeof(uint2));
    int*      csr     = (int*)alloc((size_t)(E + n) * sizeof(int));

    k_setup<<<dim3(64), dim3(256), 0, stream>>>(bcurs, bnsum, NB, n, E, offs,
                                                W1, W2, Wc, as1, ad1, as2, ad2,
                                                Wt1, Wt2, Wtc, wsd1, wsd2);
    k_binA<<<dim3((E + 4095) / 4096), dim3(256), 0, stream>>>(src, dst, E, bcurs, bucket, NB);
    k_fillB<<<dim3(NB), dim3(256), 0, stream>>>(bucket, bcurs, n, NB, offs, csr);

    dim3 ggrid((n + 63) / 64);
    dim3 wgrid((n + 3) / 4);

    // layer 1
    k_gemm_mfma<<<ggrid, 256, 0, stream>>>(x, nullptr, Wt1, wsd1, nullptr, nullptr,
                                           nullptr, invn, Hh, alpha_s, alpha_d, n, 0);
    k_agg<<<wgrid, 256, 0, stream>>>((const unsigned*)Hh, offs, csr, alpha_s, alpha_d,
                                     b1, bufB, n);
    k_bnstats<<<dim3(256), dim3(256), 0, stream>>>(bufB, n, bnsum);

    // layer 2 (BN1+relu from raw sums inside GEMM2 staging, bf16 input)
    k_gemm_mfma<<<ggrid, 256, 0, stream>>>(nullptr, bufB, Wt2, wsd2, bnsum, g1,
                                           be1, invn, Hh, alpha_s, alpha_d, n, 1);
    k_agg<<<wgrid, 256, 0, stream>>>((const unsigned*)Hh, offs, csr, alpha_s, alpha_d,
                                     b2, bufB, n);
    k_bnstats<<<dim3(256), dim3(256), 0, stream>>>(bufB, n, bnsum + 256);

    // classifier (MFMA, BN2+relu fused in staging)
    k_cls<<<ggrid, 256, 0, stream>>>(bufB, Wtc, bc, bnsum + 256, g2, be2, invn, out, n);
}

// Round 7
// 424.656 us; speedup vs baseline: 1.1314x; 1.0269x over previous
//
#include <hip/hip_runtime.h>
#include <hip/hip_fp16.h>
#include <math.h>

// GAT 2-layer + BN + classifier, MI355X.
// R17 = R16 + fat kernel k_pre: layer-1 GEMM blocks [0,gemmN) run
// concurrently with edge-binning blocks [gemmN, gemmN+binN) in ONE launch
// (independent inputs; both need only k_setup). Shared mem is a union.
// Probes the ~300us hidden outside k_agg: if k_pre >67us it surfaces in
// top-5; if total unchanged, launch gaps aren't the cost.
// k_agg = R11/R16 exact (at compulsory-fabric-traffic floor ~67us).

#define CDIM 128
#define NCLS_ 40
#define NEG_SLOPE_ 0.2f
#define BN_EPS_ 1e-5f
#define BRNG 256        // nodes per bucket (power of 2)
#define BCAP 6144       // max edges per bucket (mean 4096)
#define EPB 16          // edges per thread in binA phase (4096 per block)

using short8  = __attribute__((ext_vector_type(8))) short;
using short4v = __attribute__((ext_vector_type(4))) short;
using f32x4   = __attribute__((ext_vector_type(4))) float;

static __device__ __forceinline__ float lrelu(float a) {
    return a > 0.f ? a : NEG_SLOPE_ * a;
}
// fp32 -> bf16 round-to-nearest-even
static __device__ __forceinline__ short f2bf(float f) {
    unsigned u = __float_as_uint(f);
    u += 0x7fffu + ((u >> 16) & 1u);
    return (short)(u >> 16);
}
static __device__ __forceinline__ float bf_lo(unsigned u) { return __uint_as_float(u << 16); }
static __device__ __forceinline__ float bf_hi(unsigned u) { return __uint_as_float(u & 0xffff0000u); }
static __device__ __forceinline__ __half2 u2h2(unsigned u) { return __builtin_bit_cast(__half2, u); }
static __device__ __forceinline__ unsigned h22u(__half2 h) { return __builtin_bit_cast(unsigned, h); }

// ---------------- setup: cursors=0, bn sums=0, offs[n], W->bf16^T, ws/wd ---
__global__ void k_setup(int* bcur, float* bnsum, int NB, int n, int E, int* offs,
                        const float* __restrict__ W1, const float* __restrict__ W2,
                        const float* __restrict__ Wc,
                        const float* __restrict__ as1, const float* __restrict__ ad1,
                        const float* __restrict__ as2, const float* __restrict__ ad2,
                        short* __restrict__ Wt1, short* __restrict__ Wt2,
                        short* __restrict__ Wtc,
                        short* __restrict__ wsd1, short* __restrict__ wsd2) {
    int i = blockIdx.x * blockDim.x + threadIdx.x;
    if (i < NB) bcur[i] = 0;
    if (i < 512) bnsum[i] = 0.f;
    if (i == 0) offs[n] = E + n;
    if (i < 128 * 128) {
        int k = i >> 7, nn = i & 127;
        Wt1[nn * 128 + k] = f2bf(W1[i]);
        Wt2[nn * 128 + k] = f2bf(W2[i]);
    }
    if (i < 48 * 128) {             // padded bf16 Wc^T [48][128]
        int nn = i >> 7, k = i & 127;
        Wtc[i] = (nn < NCLS_) ? f2bf(Wc[k * NCLS_ + nn]) : (short)0;
    }
    if (i < 128) {                  // ws = W @ a_s, wd = W @ a_d (both layers)
        float s1 = 0.f, d1 = 0.f, s2 = 0.f, d2 = 0.f;
        for (int nn2 = 0; nn2 < 128; nn2++) {
            float w1v = W1[i * 128 + nn2], w2v = W2[i * 128 + nn2];
            s1 = fmaf(w1v, as1[nn2], s1); d1 = fmaf(w1v, ad1[nn2], d1);
            s2 = fmaf(w2v, as2[nn2], s2); d2 = fmaf(w2v, ad2[nn2], d2);
        }
        wsd1[i] = f2bf(s1); wsd1[128 + i] = f2bf(d1);
        wsd2[i] = f2bf(s2); wsd2[128 + i] = f2bf(d2);
    }
}

// ---------------- FAT: layer-1 GEMM (blocks<gemmN) || edge binning ---------
__global__ __launch_bounds__(256) void k_pre(
    const float* __restrict__ Xf, const short* __restrict__ Wt,
    const short* __restrict__ wsd, short* __restrict__ Hh,
    float* __restrict__ alpha_s, float* __restrict__ alpha_d, int n, int gemmN,
    const int* __restrict__ src, const int* __restrict__ dst, int E,
    int* __restrict__ bcur, uint2* __restrict__ bucket, int NB)
{
    __shared__ union {
        struct { short As[64 * 128]; short Bs[128 * 128]; short wl[256]; } g;
        struct { int hist[400]; int base[400]; } b;
    } sm;
    int t = threadIdx.x;

    if (blockIdx.x >= gemmN) {
        // ---------------- binA body ----------------
        int bid = blockIdx.x - gemmN;
        int* hist = sm.b.hist;
        int* base = sm.b.base;
        long e0 = (long)bid * (256 * EPB) + t;

        for (int i = t; i < NB; i += 256) hist[i] = 0;
        __syncthreads();

        int sv[EPB], dv[EPB];
        #pragma unroll
        for (int i = 0; i < EPB; i++) {
            long e = e0 + (long)i * 256;
            if (e < E) {
                sv[i] = src[e]; dv[i] = dst[e];
                atomicAdd(&hist[dv[i] >> 8], 1);
            } else dv[i] = -1;
        }
        __syncthreads();

        for (int i = t; i < NB; i += 256) {
            int h = hist[i];
            base[i] = (h > 0) ? atomicAdd(&bcur[i], h) : 0;
        }
        __syncthreads();
        for (int i = t; i < NB; i += 256) hist[i] = 0;   // reuse as cursor
        __syncthreads();

        #pragma unroll
        for (int i = 0; i < EPB; i++) {
            if (dv[i] >= 0) {
                int b = dv[i] >> 8;
                int pos = base[b] + atomicAdd(&hist[b], 1);
                if (pos < BCAP)
                    bucket[(size_t)b * BCAP + pos] =
                        make_uint2((unsigned)sv[i], (unsigned)dv[i]);
            }
        }
        return;
    }

    // ---------------- layer-1 GEMM body (fp32 input, no BN fuse) ----------
    short* As = sm.g.As;
    short* Bs = sm.g.Bs;
    short* wl = sm.g.wl;
    int row0 = blockIdx.x * 64;

    for (int j = 0; j < 8; j++) {
        int idx = j * 256 + t;
        int nn = idx >> 4, cc = idx & 15;
        *(short8*)(Bs + nn * 128 + cc * 8) = *(const short8*)(Wt + nn * 128 + cc * 8);
    }
    if (t < 256) wl[t] = wsd[t];
    for (int j = 0; j < 8; j++) {
        int idx = j * 256 + t;
        int r = idx >> 5, k4 = idx & 31;
        int gr = row0 + r;
        float4 xv = make_float4(0.f, 0.f, 0.f, 0.f);
        if (gr < n) xv = *(const float4*)(Xf + (size_t)gr * CDIM + k4 * 4);
        short4v o;
        o.x = f2bf(xv.x); o.y = f2bf(xv.y); o.z = f2bf(xv.z); o.w = f2bf(xv.w);
        *(short4v*)(As + r * 128 + k4 * 4) = o;
    }
    __syncthreads();

    int w = t >> 6, lane = t & 63, q = lane >> 4, c = lane & 15;
    f32x4 zero = {0.f, 0.f, 0.f, 0.f};
    f32x4 acc[4][2];
    f32x4 acc_a = zero;               // alpha: col0=alpha_s, col1=alpha_d
    for (int i = 0; i < 4; i++) { acc[i][0] = zero; acc[i][1] = zero; }

    for (int ks = 0; ks < 4; ks++) {
        int k0 = ks * 32 + q * 8;
        short8 a0 = *(short8*)(As + (c) * 128 + k0);
        short8 a1 = *(short8*)(As + (16 + c) * 128 + k0);
        short8 a2 = *(short8*)(As + (32 + c) * 128 + k0);
        short8 a3 = *(short8*)(As + (48 + c) * 128 + k0);
        short8 b0 = *(short8*)(Bs + (w * 32 + c) * 128 + k0);
        short8 b1 = *(short8*)(Bs + (w * 32 + 16 + c) * 128 + k0);
        acc[0][0] = __builtin_amdgcn_mfma_f32_16x16x32_bf16(a0, b0, acc[0][0], 0, 0, 0);
        acc[1][0] = __builtin_amdgcn_mfma_f32_16x16x32_bf16(a1, b0, acc[1][0], 0, 0, 0);
        acc[2][0] = __builtin_amdgcn_mfma_f32_16x16x32_bf16(a2, b0, acc[2][0], 0, 0, 0);
        acc[3][0] = __builtin_amdgcn_mfma_f32_16x16x32_bf16(a3, b0, acc[3][0], 0, 0, 0);
        acc[0][1] = __builtin_amdgcn_mfma_f32_16x16x32_bf16(a0, b1, acc[0][1], 0, 0, 0);
        acc[1][1] = __builtin_amdgcn_mfma_f32_16x16x32_bf16(a1, b1, acc[1][1], 0, 0, 0);
        acc[2][1] = __builtin_amdgcn_mfma_f32_16x16x32_bf16(a2, b1, acc[2][1], 0, 0, 0);
        acc[3][1] = __builtin_amdgcn_mfma_f32_16x16x32_bf16(a3, b1, acc[3][1], 0, 0, 0);

        short8 ba;
        #pragma unroll
        for (int jj = 0; jj < 8; jj++) {
            short vs = wl[k0 + jj], vd = wl[128 + k0 + jj];
            ba[jj] = (c == 0) ? vs : ((c == 1) ? vd : (short)0);
        }
        short8 aw = (w == 0) ? a0 : ((w == 1) ? a1 : ((w == 2) ? a2 : a3));
        acc_a = __builtin_amdgcn_mfma_f32_16x16x32_bf16(aw, ba, acc_a, 0, 0, 0);
    }

    __syncthreads();                  // all As reads done before reuse

    short* Hs = As;
    #pragma unroll
    for (int mt = 0; mt < 4; mt++)
        #pragma unroll
        for (int nt = 0; nt < 2; nt++)
            #pragma unroll
            for (int r = 0; r < 4; r++)
                Hs[(mt * 16 + q * 4 + r) * 128 + w * 32 + nt * 16 + c] =
                    (short)__half_as_ushort(__float2half_rn(acc[mt][nt][r]));

    if (c < 2) {
        #pragma unroll
        for (int r = 0; r < 4; r++) {
            int row = row0 + w * 16 + q * 4 + r;
            if (row < n) {
                if (c == 0) alpha_s[row] = acc_a[r];
                else        alpha_d[row] = acc_a[r];
            }
        }
    }
    __syncthreads();

    for (int j = 0; j < 4; j++) {
        int idx = j * 256 + t;
        int r = idx >> 4, cc = idx & 15;
        int gr = row0 + r;
        if (gr < n)
            *(short8*)(Hh + (size_t)gr * 128 + cc * 8) = *(short8*)(Hs + r * 128 + cc * 8);
    }
}

// ---------------- per-bucket CSR build in LDS ------------------------------
__global__ __launch_bounds__(256) void k_fillB(
    const uint2* __restrict__ bucket, const int* __restrict__ bcur,
    int n, int NB, int* __restrict__ offs, int* __restrict__ csr)
{
    __shared__ int hist[256];
    __shared__ int scanb[256];
    __shared__ int cur[256];
    __shared__ int buf[BCAP + BRNG];
    int b = blockIdx.x, t = threadIdx.x;
    int node0 = b << 8;
    int nodesIn = min(BRNG, n - node0);
    int cnt = min(bcur[b], BCAP);
    const uint2* mybkt = bucket + (size_t)b * BCAP;

    int part = 0;
    for (int j = t; j < b; j += 256) part += min(bcur[j], BCAP);
    scanb[t] = part; __syncthreads();
    for (int s2 = 128; s2 > 0; s2 >>= 1) {
        if (t < s2) scanb[t] += scanb[t + s2];
        __syncthreads();
    }
    int base = scanb[0] + node0;
    __syncthreads();

    hist[t] = 0; __syncthreads();
    for (int e2 = t; e2 < cnt; e2 += 256)
        atomicAdd(&hist[mybkt[e2].y & 255], 1);
    __syncthreads();

    int v = hist[t] + ((t < nodesIn) ? 1 : 0);
    scanb[t] = v; __syncthreads();
    for (int d = 1; d < 256; d <<= 1) {
        int x2 = (t >= d) ? scanb[t - d] : 0;
        __syncthreads();
        scanb[t] += x2;
        __syncthreads();
    }
    int lo = scanb[t] - v;
    if (t < nodesIn) {
        offs[node0 + t] = base + lo;
        buf[lo] = node0 + t;          // self-loop occupies slot 0
        cur[t] = lo + 1;
    }
    __syncthreads();

    for (int e2 = t; e2 < cnt; e2 += 256) {
        uint2 ed = mybkt[e2];
        int pos = atomicAdd(&cur[ed.y & 255], 1);
        buf[pos] = (int)ed.x;
    }
    __syncthreads();

    int tot = cnt + nodesIn;
    for (int j2 = t; j2 < tot; j2 += 256) csr[base + j2] = buf[j2];
}

// ---------------- MFMA GEMM (layer 2): Hh = act(bn(G)) @ W, alpha fused ----
__global__ __launch_bounds__(256) void k_gemm_mfma(
    const unsigned* __restrict__ Xb, const short* __restrict__ Wt,
    const short* __restrict__ wsd,
    const float* __restrict__ bnsum, const float* __restrict__ gamma,
    const float* __restrict__ beta, float invn,
    short* __restrict__ Hh, float* __restrict__ alpha_s, float* __restrict__ alpha_d,
    int n)
{
    __shared__ short As[64 * 128];    // 16.4 KB (reused as H transpose buffer)
    __shared__ short Bs[128 * 128];   // 32.8 KB
    __shared__ short wl[256];         // ws (0..127), wd (128..255) bf16
    int t = threadIdx.x;
    int row0 = blockIdx.x * 64;

    for (int j = 0; j < 8; j++) {
        int idx = j * 256 + t;
        int nn = idx >> 4, cc = idx & 15;
        *(short8*)(Bs + nn * 128 + cc * 8) = *(const short8*)(Wt + nn * 128 + cc * 8);
    }
    if (t < 256) wl[t] = wsd[t];
    float4 sc4, sh4;
    {
        int cb = (t & 31) * 4;
        float4 s0 = *(const float4*)(bnsum + cb);
        float4 s1 = *(const float4*)(bnsum + 128 + cb);
        float4 gm = *(const float4*)(gamma + cb);
        float4 bt = *(const float4*)(beta + cb);
        float mean, var;
        mean = s0.x * invn; var = fmaxf(s1.x * invn - mean * mean, 0.f);
        sc4.x = gm.x * rsqrtf(var + BN_EPS_); sh4.x = bt.x - mean * sc4.x;
        mean = s0.y * invn; var = fmaxf(s1.y * invn - mean * mean, 0.f);
        sc4.y = gm.y * rsqrtf(var + BN_EPS_); sh4.y = bt.y - mean * sc4.y;
        mean = s0.z * invn; var = fmaxf(s1.z * invn - mean * mean, 0.f);
        sc4.z = gm.z * rsqrtf(var + BN_EPS_); sh4.z = bt.z - mean * sc4.z;
        mean = s0.w * invn; var = fmaxf(s1.w * invn - mean * mean, 0.f);
        sc4.w = gm.w * rsqrtf(var + BN_EPS_); sh4.w = bt.w - mean * sc4.w;
    }
    for (int j = 0; j < 8; j++) {
        int idx = j * 256 + t;
        int r = idx >> 5, k4 = idx & 31;
        int gr = row0 + r;
        float4 xv = make_float4(0.f, 0.f, 0.f, 0.f);
        if (gr < n) {
            uint2 u = *(const uint2*)(Xb + (size_t)gr * 64 + k4 * 2);
            xv.x = bf_lo(u.x); xv.y = bf_hi(u.x);
            xv.z = bf_lo(u.y); xv.w = bf_hi(u.y);
        }
        xv.x = fmaxf(fmaf(xv.x, sc4.x, sh4.x), 0.f);
        xv.y = fmaxf(fmaf(xv.y, sc4.y, sh4.y), 0.f);
        xv.z = fmaxf(fmaf(xv.z, sc4.z, sh4.z), 0.f);
        xv.w = fmaxf(fmaf(xv.w, sc4.w, sh4.w), 0.f);
        short4v o;
        o.x = f2bf(xv.x); o.y = f2bf(xv.y); o.z = f2bf(xv.z); o.w = f2bf(xv.w);
        *(short4v*)(As + r * 128 + k4 * 4) = o;
    }
    __syncthreads();

    int w = t >> 6, lane = t & 63, q = lane >> 4, c = lane & 15;
    f32x4 zero = {0.f, 0.f, 0.f, 0.f};
    f32x4 acc[4][2];
    f32x4 acc_a = zero;
    for (int i = 0; i < 4; i++) { acc[i][0] = zero; acc[i][1] = zero; }

    for (int ks = 0; ks < 4; ks++) {
        int k0 = ks * 32 + q * 8;
        short8 a0 = *(short8*)(As + (c) * 128 + k0);
        short8 a1 = *(short8*)(As + (16 + c) * 128 + k0);
        short8 a2 = *(short8*)(As + (32 + c) * 128 + k0);
        short8 a3 = *(short8*)(As + (48 + c) * 128 + k0);
        short8 b0 = *(short8*)(Bs + (w * 32 + c) * 128 + k0);
        short8 b1 = *(short8*)(Bs + (w * 32 + 16 + c) * 128 + k0);
        acc[0][0] = __builtin_amdgcn_mfma_f32_16x16x32_bf16(a0, b0, acc[0][0], 0, 0, 0);
        acc[1][0] = __builtin_amdgcn_mfma_f32_16x16x32_bf16(a1, b0, acc[1][0], 0, 0, 0);
        acc[2][0] = __builtin_amdgcn_mfma_f32_16x16x32_bf16(a2, b0, acc[2][0], 0, 0, 0);
        acc[3][0] = __builtin_amdgcn_mfma_f32_16x16x32_bf16(a3, b0, acc[3][0], 0, 0, 0);
        acc[0][1] = __builtin_amdgcn_mfma_f32_16x16x32_bf16(a0, b1, acc[0][1], 0, 0, 0);
        acc[1][1] = __builtin_amdgcn_mfma_f32_16x16x32_bf16(a1, b1, acc[1][1], 0, 0, 0);
        acc[2][1] = __builtin_amdgcn_mfma_f32_16x16x32_bf16(a2, b1, acc[2][1], 0, 0, 0);
        acc[3][1] = __builtin_amdgcn_mfma_f32_16x16x32_bf16(a3, b1, acc[3][1], 0, 0, 0);

        short8 ba;
        #pragma unroll
        for (int jj = 0; jj < 8; jj++) {
            short vs = wl[k0 + jj], vd = wl[128 + k0 + jj];
            ba[jj] = (c == 0) ? vs : ((c == 1) ? vd : (short)0);
        }
        short8 aw = (w == 0) ? a0 : ((w == 1) ? a1 : ((w == 2) ? a2 : a3));
        acc_a = __builtin_amdgcn_mfma_f32_16x16x32_bf16(aw, ba, acc_a, 0, 0, 0);
    }

    __syncthreads();

    short* Hs = As;
    #pragma unroll
    for (int mt = 0; mt < 4; mt++)
        #pragma unroll
        for (int nt = 0; nt < 2; nt++)
            #pragma unroll
            for (int r = 0; r < 4; r++)
                Hs[(mt * 16 + q * 4 + r) * 128 + w * 32 + nt * 16 + c] =
                    (short)__half_as_ushort(__float2half_rn(acc[mt][nt][r]));

    if (c < 2) {
        #pragma unroll
        for (int r = 0; r < 4; r++) {
            int row = row0 + w * 16 + q * 4 + r;
            if (row < n) {
                if (c == 0) alpha_s[row] = acc_a[r];
                else        alpha_d[row] = acc_a[r];
            }
        }
    }
    __syncthreads();

    for (int j = 0; j < 4; j++) {
        int idx = j * 256 + t;
        int r = idx >> 4, cc = idx & 15;
        int gr = row0 + r;
        if (gr < n)
            *(short8*)(Hh + (size_t)gr * 128 + cc * 8) = *(short8*)(Hs + r * 128 + cc * 8);
    }
}

// ---------------- ONE-PASS softmax + aggregation (one wave per node) -------
// R11 exact: all <=24 row-gathers issued BEFORE the alpha gather + softmax
// (loads depend only on sj), 3-deep batch pipeline for degree>24.
__global__ __launch_bounds__(256) void k_agg(
    const unsigned* __restrict__ Hh, const int* __restrict__ offs,
    const int* __restrict__ csr, const float* __restrict__ alpha_s,
    const float* __restrict__ alpha_d, const float* __restrict__ bias,
    unsigned* __restrict__ Ob, int n)
{
    int i = blockIdx.x * 4 + (threadIdx.x >> 6);
    int lane = threadIdx.x & 63;
    if (i >= n) return;
    int o0 = offs[i], o1 = offs[i + 1];
    float adi = alpha_d[i];

    float m = -1e30f;
    float se = 0.f;
    __half2 acc2 = __floats2half2_rn(0.f, 0.f);

    for (int c0 = o0; c0 < o1; c0 += 64) {
        int j = c0 + lane;
        int cnt = min(64, o1 - c0);
        int sj = (j < o1) ? csr[j] : 0;   // invalid lanes -> row 0 (w=0)

        // ---- issue up to 24 H-row gathers now (independent of weights) ----
        unsigned ua[8], ub[8], uc[8];
        #pragma unroll
        for (int q = 0; q < 8; q++) {
            int s = __builtin_amdgcn_readlane(sj, q);
            ua[q] = Hh[(size_t)(unsigned)s * 64 + lane];
        }
        if (cnt > 8) {
            #pragma unroll
            for (int q = 0; q < 8; q++) {
                int s = __builtin_amdgcn_readlane(sj, 8 + q);
                ub[q] = Hh[(size_t)(unsigned)s * 64 + lane];
            }
        }
        if (cnt > 16) {
            #pragma unroll
            for (int q = 0; q < 8; q++) {
                int s = __builtin_amdgcn_readlane(sj, 16 + q);
                uc[q] = Hh[(size_t)(unsigned)s * 64 + lane];
            }
        }

        // ---- softmax weights (overlaps the in-flight gathers) ----
        float a = (j < o1) ? lrelu(alpha_s[sj] + adi) : -1e30f;
        float cm = a;
        #pragma unroll
        for (int o = 32; o > 0; o >>= 1) cm = fmaxf(cm, __shfl_xor(cm, o));
        if (cm > m) {
            float r = __expf(m - cm);
            se *= r;
            acc2 = __hmul2(acc2, __float2half2_rn(r));
            m = cm;
        }
        float wl2 = (j < o1) ? __expf(a - m) : 0.f;
        se += wl2;
        int wli = (int)h22u(__float2half2_rn(wl2));

        // ---- consume + prefetch, 24 edges per iteration ----
        for (int b = 0; b < cnt; b += 24) {
            #pragma unroll
            for (int q = 0; q < 8; q++) {
                int wq = __builtin_amdgcn_readlane(wli, b + q);
                acc2 = __hfma2(u2h2(ua[q]), u2h2((unsigned)wq), acc2);
            }
            if (b + 24 < cnt) {
                #pragma unroll
                for (int q = 0; q < 8; q++) {
                    int s = __builtin_amdgcn_readlane(sj, b + 24 + q);
                    ua[q] = Hh[(size_t)(unsigned)s * 64 + lane];
                }
            }
            if (b + 8 < cnt) {
                #pragma unroll
                for (int q = 0; q < 8; q++) {
                    int wq = __builtin_amdgcn_readlane(wli, b + 8 + q);
                    acc2 = __hfma2(u2h2(ub[q]), u2h2((unsigned)wq), acc2);
                }
                if (b + 32 < cnt) {
                    #pragma unroll
                    for (int q = 0; q < 8; q++) {
                        int s = __builtin_amdgcn_readlane(sj, b + 32 + q);
                        ub[q] = Hh[(size_t)(unsigned)s * 64 + lane];
                    }
                }
                if (b + 16 < cnt) {
                    #pragma unroll
                    for (int q = 0; q < 8; q++) {
                        int wq = __builtin_amdgcn_readlane(wli, b + 16 + q);
                        acc2 = __hfma2(u2h2(uc[q]), u2h2((unsigned)wq), acc2);
                    }
                    if (b + 40 < cnt) {
                        #pragma unroll
                        for (int q = 0; q < 8; q++) {
                            int s = __builtin_amdgcn_readlane(sj, b + 40 + q);
                            uc[q] = Hh[(size_t)(unsigned)s * 64 + lane];
                        }
                    }
                }
            }
        }
    }

    #pragma unroll
    for (int o = 32; o > 0; o >>= 1) se += __shfl_xor(se, o);
    float inv = 1.f / se;
    float2 af = __half22float2(acc2);
    float2 b2 = *(const float2*)(bias + lane * 2);
    float rx = fmaf(af.x, inv, b2.x);
    float ry = fmaf(af.y, inv, b2.y);
    unsigned pack = ((unsigned)(unsigned short)f2bf(ry) << 16) |
                    (unsigned)(unsigned short)f2bf(rx);
    Ob[(size_t)i * 64 + lane] = pack;
}

// ---------------- BN stats from packed bf16: per-channel sum / sumsq -------
__global__ void k_bnstats(const unsigned* __restrict__ Hb, int n, float* __restrict__ sums) {
    __shared__ float red[4][64][4];
    int w = threadIdx.x & 63;
    int g = threadIdx.x >> 6;
    float slo = 0.f, shi = 0.f, qlo = 0.f, qhi = 0.f;
    for (int r = blockIdx.x * 4 + g; r < n; r += gridDim.x * 4) {
        unsigned u = Hb[(size_t)r * 64 + w];
        float lo = bf_lo(u), hi = bf_hi(u);
        slo += lo; shi += hi; qlo += lo * lo; qhi += hi * hi;
    }
    red[g][w][0] = slo; red[g][w][1] = shi; red[g][w][2] = qlo; red[g][w][3] = qhi;
    __syncthreads();
    if (threadIdx.x < 64) {
        int w2 = threadIdx.x;
        float s0 = 0.f, s1 = 0.f, s2 = 0.f, s3 = 0.f;
        for (int gg = 0; gg < 4; gg++) {
            s0 += red[gg][w2][0]; s1 += red[gg][w2][1];
            s2 += red[gg][w2][2]; s3 += red[gg][w2][3];
        }
        atomicAdd(&sums[2 * w2], s0);
        atomicAdd(&sums[2 * w2 + 1], s1);
        atomicAdd(&sums[128 + 2 * w2], s2);
        atomicAdd(&sums[128 + 2 * w2 + 1], s3);
    }
}

// ---------------- classifier (MFMA): out = relu(bn(G)) @ Wc + bc -----------
__global__ __launch_bounds__(256) void k_cls(
    const unsigned* __restrict__ G, const short* __restrict__ Wtc,
    const float* __restrict__ bc, const float* __restrict__ bnsum,
    const float* __restrict__ gamma, const float* __restrict__ beta, float invn,
    float* __restrict__ out, int n)
{
    __shared__ short As[64 * 128];   // 16.4 KB
    __shared__ short Bs[48 * 128];   // 12.3 KB
    int t = threadIdx.x;
    int row0 = blockIdx.x * 64;

    for (int j = 0; j < 3; j++) {
        int idx = j * 256 + t;       // 768 short8 = 6144 shorts
        *(short8*)(Bs + idx * 8) = *(const short8*)(Wtc + idx * 8);
    }
    float4 sc4, sh4;
    {
        int cb = (t & 31) * 4;
        float4 s0 = *(const float4*)(bnsum + cb);
        float4 s1 = *(const float4*)(bnsum + 128 + cb);
        float4 gm = *(const float4*)(gamma + cb);
        float4 bt = *(const float4*)(beta + cb);
        float mean, var;
        mean = s0.x * invn; var = fmaxf(s1.x * invn - mean * mean, 0.f);
        sc4.x = gm.x * rsqrtf(var + BN_EPS_); sh4.x = bt.x - mean * sc4.x;
        mean = s0.y * invn; var = fmaxf(s1.y * invn - mean * mean, 0.f);
        sc4.y = gm.y * rsqrtf(var + BN_EPS_); sh4.y = bt.y - mean * sc4.y;
        mean = s0.z * invn; var = fmaxf(s1.z * invn - mean * mean, 0.f);
        sc4.z = gm.z * rsqrtf(var + BN_EPS_); sh4.z = bt.z - mean * sc4.z;
        mean = s0.w * invn; var = fmaxf(s1.w * invn - mean * mean, 0.f);
        sc4.w = gm.w * rsqrtf(var + BN_EPS_); sh4.w = bt.w - mean * sc4.w;
    }
    for (int j = 0; j < 8; j++) {
        int idx = j * 256 + t;
        int r = idx >> 5, k4 = idx & 31;
        int gr = row0 + r;
        float4 xv = make_float4(0.f, 0.f, 0.f, 0.f);
        if (gr < n) {
            uint2 u = *(const uint2*)(G + (size_t)gr * 64 + k4 * 2);
            xv.x = bf_lo(u.x); xv.y = bf_hi(u.x);
            xv.z = bf_lo(u.y); xv.w = bf_hi(u.y);
        }
        xv.x = fmaxf(fmaf(xv.x, sc4.x, sh4.x), 0.f);
        xv.y = fmaxf(fmaf(xv.y, sc4.y, sh4.y), 0.f);
        xv.z = fmaxf(fmaf(xv.z, sc4.z, sh4.z), 0.f);
        xv.w = fmaxf(fmaf(xv.w, sc4.w, sh4.w), 0.f);
        short4v o;
        o.x = f2bf(xv.x); o.y = f2bf(xv.y); o.z = f2bf(xv.z); o.w = f2bf(xv.w);
        *(short4v*)(As + r * 128 + k4 * 4) = o;
    }
    __syncthreads();

    int w = t >> 6, lane = t & 63, q = lane >> 4, c = lane & 15;
    f32x4 zero = {0.f, 0.f, 0.f, 0.f};
    f32x4 acc[3] = {zero, zero, zero};
    for (int ks = 0; ks < 4; ks++) {
        int k0 = ks * 32 + q * 8;
        short8 a  = *(short8*)(As + (w * 16 + c) * 128 + k0);
        short8 b0 = *(short8*)(Bs + (c) * 128 + k0);
        short8 b1 = *(short8*)(Bs + (16 + c) * 128 + k0);
        short8 b2 = *(short8*)(Bs + (32 + c) * 128 + k0);
        acc[0] = __builtin_amdgcn_mfma_f32_16x16x32_bf16(a, b0, acc[0], 0, 0, 0);
        acc[1] = __builtin_amdgcn_mfma_f32_16x16x32_bf16(a, b1, acc[1], 0, 0, 0);
        acc[2] = __builtin_amdgcn_mfma_f32_16x16x32_bf16(a, b2, acc[2], 0, 0, 0);
    }
    float bc0 = bc[c], bc1 = bc[16 + c], bc2 = (c < 8) ? bc[32 + c] : 0.f;
    #pragma unroll
    for (int r = 0; r < 4; r++) {
        int row = row0 + w * 16 + q * 4 + r;
        if (row < n) {
            out[(size_t)row * NCLS_ + c]      = acc[0][r] + bc0;
            out[(size_t)row * NCLS_ + 16 + c] = acc[1][r] + bc1;
            if (c < 8) out[(size_t)row * NCLS_ + 32 + c] = acc[2][r] + bc2;
        }
    }
}

// ---------------- launch ---------------------------------------------------
extern "C" void kernel_launch(void* const* d_in, const int* in_sizes, int n_in,
                              void* d_out, int out_size, void* d_ws, size_t ws_size,
                              hipStream_t stream)
{
    const float* x   = (const float*)d_in[0];
    const int*   ei  = (const int*)d_in[1];
    const float* W1  = (const float*)d_in[2];
    const float* as1 = (const float*)d_in[3];
    const float* ad1 = (const float*)d_in[4];
    const float* b1  = (const float*)d_in[5];
    const float* g1  = (const float*)d_in[6];
    const float* be1 = (const float*)d_in[7];
    const float* W2  = (const float*)d_in[8];
    const float* as2 = (const float*)d_in[9];
    const float* ad2 = (const float*)d_in[10];
    const float* b2  = (const float*)d_in[11];
    const float* g2  = (const float*)d_in[12];
    const float* be2 = (const float*)d_in[13];
    const float* Wc  = (const float*)d_in[14];
    const float* bc  = (const float*)d_in[15];
    float* out = (float*)d_out;

    int n = in_sizes[0] / CDIM;     // 100000
    int E = in_sizes[1] / 2;        // 1600000
    const int* src = ei;
    const int* dst = ei + E;
    float invn = 1.f / (float)n;
    int NB = (n + BRNG - 1) / BRNG; // 391

    // workspace layout (64B-aligned chunks)
    char* p = (char*)d_ws;
    auto alloc = [&p](size_t bytes) { char* q = p; p += (bytes + 63) & ~(size_t)63; return q; };
    short*    Hh      = (short*)alloc((size_t)n * CDIM * sizeof(short));
    unsigned* bufB    = (unsigned*)alloc((size_t)n * 64 * sizeof(unsigned));
    float*    alpha_s = (float*)alloc((size_t)n * sizeof(float));
    float*    alpha_d = (float*)alloc((size_t)n * sizeof(float));
    float*    bnsum   = (float*)alloc(512 * sizeof(float));
    short*    Wt1     = (short*)alloc(128 * 128 * sizeof(short));
    short*    Wt2     = (short*)alloc(128 * 128 * sizeof(short));
    short*    Wtc     = (short*)alloc(48 * 128 * sizeof(short));
    short*    wsd1    = (short*)alloc(256 * sizeof(short));
    short*    wsd2    = (short*)alloc(256 * sizeof(short));
    int*      bcurs   = (int*)alloc((size_t)NB * sizeof(int));
    int*      offs    = (int*)alloc((size_t)(n + 1) * sizeof(int));
    uint2*    bucket  = (uint2*)alloc((size_t)NB * BCAP * sizeof(uint2));
    int*      csr     = (int*)alloc((size_t)(E + n) * sizeof(int));

    k_setup<<<dim3(64), dim3(256), 0, stream>>>(bcurs, bnsum, NB, n, E, offs,
                                                W1, W2, Wc, as1, ad1, as2, ad2,
                                                Wt1, Wt2, Wtc, wsd1, wsd2);

    int gemmN = (n + 63) / 64;            // 1563
    int binN  = (E + 4095) / 4096;        // 391
    // fat: layer-1 GEMM || edge binning (independent; both only need k_setup)
    k_pre<<<dim3(gemmN + binN), dim3(256), 0, stream>>>(
        x, Wt1, wsd1, Hh, alpha_s, alpha_d, n, gemmN,
        src, dst, E, bcurs, bucket, NB);

    k_fillB<<<dim3(NB), dim3(256), 0, stream>>>(bucket, bcurs, n, NB, offs, csr);

    dim3 ggrid(gemmN);
    dim3 wgrid((n + 3) / 4);

    // layer 1 aggregation + BN stats
    k_agg<<<wgrid, 256, 0, stream>>>((const unsigned*)Hh, offs, csr, alpha_s, alpha_d,
                                     b1, bufB, n);
    k_bnstats<<<dim3(256), dim3(256), 0, stream>>>(bufB, n, bnsum);

    // layer 2 (BN1+relu from raw sums inside GEMM2 staging, bf16 input)
    k_gemm_mfma<<<ggrid, 256, 0, stream>>>(bufB, Wt2, wsd2, bnsum, g1, be1,
                                           invn, Hh, alpha_s, alpha_d, n);
    k_agg<<<wgrid, 256, 0, stream>>>((const unsigned*)Hh, offs, csr, alpha_s, alpha_d,
                                     b2, bufB, n);
    k_bnstats<<<dim3(256), dim3(256), 0, stream>>>(bufB, n, bnsum + 256);

    // classifier (MFMA, BN2+relu fused in staging)
    k_cls<<<ggrid, 256, 0, stream>>>(bufB, Wtc, bc, bnsum + 256, g2, be2, invn, out, n);
}